// Round 15
// baseline (239.211 us; speedup 1.0000x reference)
//
#include <hip/hip_runtime.h>
#include <hip/hip_bf16.h>
#include <math.h>

typedef __bf16 bf16x8 __attribute__((ext_vector_type(8)));
typedef float  f32x4  __attribute__((ext_vector_type(4)));

static constexpr int BN2 = 2;
static constexpr int CA = 256, HA = 64, WA = 128;   // stage A input
static constexpr int OO = 128;                      // output channels
static constexpr int HC = 128, WC = 256, CC = 128;  // stage C

// ---------- pack weights into MFMA B-fragment layout: [9][C/32][OT][64][8] bf16 ----------
__global__ void pack_w_kernel(const float* __restrict__ w, __bf16* __restrict__ out,
                              int Cin, int OT, int Oreal) {
    int NCH = Cin / 32;
    int idx = blockIdx.x * blockDim.x + threadIdx.x;
    int total = 9 * NCH * OT * 512;
    if (idx >= total) return;
    int j    = idx & 7;
    int lane = (idx >> 3) & 63;
    int ot   = (idx >> 9) % OT;
    int rest = (idx >> 9) / OT;
    int ch = rest % NCH;
    int k  = rest / NCH;
    int o = ot * 16 + (lane & 15);
    int c = ch * 32 + (lane >> 4) * 8 + j;
    float v = (o < Oreal) ? w[((size_t)o * Cin + c) * 9 + k] : 0.f;
    out[idx] = (__bf16)v;
}

// ---------- NCHW fp32 -> NHWC bf16 (LDS tile transpose) ----------
template<int C, int HW>
__global__ __launch_bounds__(256) void to_cl_kernel(const float* __restrict__ x,
                                                    __bf16* __restrict__ xcl) {
    constexpr int NCB = C / 32;
    constexpr int NPB = HW / 64;
    int blk = blockIdx.x;
    int pblk = blk % NPB;
    int cblk = (blk / NPB) % NCB;
    int b = blk / (NPB * NCB);
    int t = threadIdx.x;
    __shared__ float st[32][65];
    int r = t >> 6, q = t & 63;
#pragma unroll
    for (int i = 0; i < 8; i++) {
        int c = cblk * 32 + i * 4 + r;
        st[i * 4 + r][q] = x[((size_t)b * C + c) * HW + pblk * 64 + q];
    }
    __syncthreads();
    int p = t >> 2, cq = t & 3;
    bf16x8 v;
#pragma unroll
    for (int j = 0; j < 8; j++) v[j] = (__bf16)st[cq * 8 + j][p];
    *reinterpret_cast<bf16x8*>(xcl + ((size_t)b * HW + pblk * 64 + p) * C + cblk * 32 + cq * 8) = v;
}

// ---------- fold bias+BN into per-o scale/shift ----------
__global__ void bn_prepack_kernel(const float* __restrict__ g,  const float* __restrict__ be,
                                  const float* __restrict__ mu, const float* __restrict__ va,
                                  const float* __restrict__ bi,
                                  float* __restrict__ sc, float* __restrict__ sh) {
    int i = blockIdx.x * blockDim.x + threadIdx.x;
    if (i >= OO) return;
    float s = g[i] * rsqrtf(va[i] + 1e-5f);
    sc[i] = s;
    sh[i] = (bi[i] - mu[i]) * s + be[i];
}

// ---------- upw[O][4][4] -> upwt[16][O] ----------
__global__ void pack_upw_kernel(const float* __restrict__ upw, float* __restrict__ upwt) {
    int idx = blockIdx.x * blockDim.x + threadIdx.x;
    if (idx >= 16 * OO) return;
    int i = idx >> 7;
    int o = idx & 127;
    upwt[i * OO + o] = upw[o * 16 + i];
}

// ---------- om-conv as MFMA, bf16 window (WS=198) — r13-proven ----------
template<int C, int H, int W>
__global__ __launch_bounds__(256) void om_mfma_kernel(
    const __bf16* __restrict__ xcl,   // [B][H][W][C]
    const __bf16* __restrict__ womp,  // [9][C/32][2][64][8] bf16
    const float* __restrict__ bom,    // [27]
    float* __restrict__ omcl)         // [B][H][W][32]
{
    constexpr int NCH = C / 32;
    constexpr int WS = 198;           // 3*66 exactly; bf16 window halves LDS
    const int nwt = W / 64;
    int wt = blockIdx.x % nwt;
    int h  = (blockIdx.x / nwt) % H;
    int b  = blockIdx.x / (nwt * H);
    int t = threadIdx.x;
    int wave = t >> 6, lane = t & 63;
    int row = lane & 15, kg = lane >> 4;

    __shared__ __bf16 win[32 * WS];   // 12672 B

    f32x4 acc0 = {0.f, 0.f, 0.f, 0.f};
    f32x4 acc1 = {0.f, 0.f, 0.f, 0.f};
    const __bf16* xb = xcl + (size_t)b * H * W * C;

    for (int ch = 0; ch < NCH; ch++) {
        for (int i = 0; i < 4; i++) {
            int idx = i * 256 + t;
            if (idx < 792) {
                int cq  = idx & 3;
                int pix = idx >> 2;
                int ry = pix / 66, rx = pix % 66;
                int y = h + ry - 1, xx = wt * 64 + rx - 1;
                bool valid = (y >= 0) && (y < H) && (xx >= 0) && (xx < W);
                int yc = min(max(y, 0), H - 1), xc = min(max(xx, 0), W - 1);
                uint4 u = *reinterpret_cast<const uint4*>(
                    xb + ((size_t)yc * W + xc) * C + ch * 32 + cq * 8);
                if (!valid) { u.x = 0; u.y = 0; u.z = 0; u.w = 0; }
                bf16x8 v = __builtin_bit_cast(bf16x8, u);
#pragma unroll
                for (int j = 0; j < 8; j++)
                    win[(cq * 8 + j) * WS + pix] = v[j];
            }
        }
        __syncthreads();
#pragma unroll
        for (int k = 0; k < 9; k++) {
            int off = (k / 3) * 66 + (k % 3) + wave * 16 + row;
            bf16x8 a;
#pragma unroll
            for (int j = 0; j < 8; j++)
                a[j] = win[(kg * 8 + j) * WS + off];
            const __bf16* wbc = womp + ((size_t)k * NCH + ch) * 1024 + lane * 8;
            bf16x8 b0 = *reinterpret_cast<const bf16x8*>(wbc);
            bf16x8 b1 = *reinterpret_cast<const bf16x8*>(wbc + 512);
            acc0 = __builtin_amdgcn_mfma_f32_16x16x32_bf16(a, b0, acc0, 0, 0, 0);
            acc1 = __builtin_amdgcn_mfma_f32_16x16x32_bf16(a, b1, acc1, 0, 0, 0);
        }
        __syncthreads();
    }

    float* ob = omcl + (((size_t)b * H + h) * W + wt * 64 + wave * 16 + kg * 4) * 32;
    float bb0 = bom[row];
#pragma unroll
    for (int j = 0; j < 4; j++)
        ob[(size_t)j * 32 + row] = acc0[j] + bb0;
    if (row < 11) {
        float bb1 = bom[16 + row];
#pragma unroll
        for (int j = 0; j < 4; j++)
            ob[(size_t)j * 32 + 16 + row] = acc1[j] + bb1;
    }
}

// ---------- DCN v8: gather lanes == A-frag lanes -> NO LDS round-trip in main loop ----------
// Gather roles: p = lane&15 (position), kg = lane>>4 (channel octet). 4 lanes {p,p+16,p+32,p+48}
// read the same pixel's contiguous 64B (same 16 aligned segments per instr as before).
// Blend output IS the A-fragment. B-frags prefetched BEFORE gathers (r11 ordering);
// two g-sets give ~2 steps of drain with clean vmcnt ordering.
template<int C, int H, int W, int KS, bool CF_OUT>
__global__ __launch_bounds__(64 * KS) void dcn_mfma8_kernel(
    const __bf16* __restrict__ xcl,  // [B][H][W][C]
    const float* __restrict__ omcl,  // [B][H][W][32]
    const __bf16* __restrict__ wkp,  // [9][C/32][8][64][8] bf16 (pack_w)
    const float* __restrict__ sc, const float* __restrict__ sh,
    float* __restrict__ outcf,       // CF_OUT: [B][O][H][W] fp32
    __bf16* __restrict__ outcl)      // else:   [B][H][W][O] bf16
{
    constexpr int NCH = C / 32;      // 32-channel chunks
    constexpr int CHW = NCH / KS;    // chunks per wave
    constexpr int NSW = 9 * CHW;     // steps per wave (even for both stages)
    static_assert(NSW % 2 == 0, "unroll-by-2 needs even NSW");
    constexpr int MAIN = 4608;                      // pk only (no staging LDS)
    constexpr int RED  = (KS - 1) * 9216;           // reduce slices (alias, post-barrier)
    constexpr int SMEM = MAIN > RED ? MAIN : RED;

    const int nwt = W / 16;
    int wt = blockIdx.x % nwt;
    int h  = (blockIdx.x / nwt) % H;
    int b  = blockIdx.x / (nwt * H);
    int t = threadIdx.x;
    int wave = t >> 6, lane = t & 63;
    int row = lane & 15, kg = lane >> 4;     // SAME roles for gather and MFMA

    __shared__ __align__(16) char smem[SMEM];
    int4*   pki  = reinterpret_cast<int4*>(smem);            // [144]
    float4* pkw  = reinterpret_cast<float4*>(smem + 2304);   // [144]

    // per-(pos,k) precompute (r5-proven math, 16-pos tile)
    const float* omb = omcl + (((size_t)b * H + h) * W + wt * 16) * 32;
    for (int idx = t; idx < 144; idx += 64 * KS) {
        int p = idx & 15;
        int k = idx >> 4;
        float o1 = omb[p * 32 + k];
        float o2 = omb[p * 32 + 9 + k];
        float mm = omb[p * 32 + 18 + k];
        mm = 1.f / (1.f + expf(-mm));
        float py = o1 + (float)(h + k / 3 - 1);
        float px = o2 + (float)(wt * 16 + p + k % 3 - 1);
        float y0f = floorf(py), x0f = floorf(px);
        float wy = py - y0f, wx = px - x0f;
        int y0 = (int)y0f, x0 = (int)x0f;
        bool y0v = (y0 >= 0) && (y0 < H);
        bool y1v = (y0 + 1 >= 0) && (y0 + 1 < H);
        bool x0v = (x0 >= 0) && (x0 < W);
        bool x1v = (x0 + 1 >= 0) && (x0 + 1 < W);
        int y0c = min(max(y0, 0), H - 1) * W;
        int y1c = min(max(y0 + 1, 0), H - 1) * W;
        int x0c = min(max(x0, 0), W - 1);
        int x1c = min(max(x0 + 1, 0), W - 1);
        int4 pi;
        pi.x = (y0c + x0c) * C; pi.y = (y0c + x1c) * C;
        pi.z = (y1c + x0c) * C; pi.w = (y1c + x1c) * C;
        float4 pw;
        pw.x = (y0v && x0v) ? (1.f - wy) * (1.f - wx) * mm : 0.f;
        pw.y = (y0v && x1v) ? (1.f - wy) * wx * mm : 0.f;
        pw.z = (y1v && x0v) ? wy * (1.f - wx) * mm : 0.f;
        pw.w = (y1v && x1v) ? wy * wx * mm : 0.f;
        pki[idx] = pi;
        pkw[idx] = pw;
    }
    __syncthreads();

    f32x4 acc[8];
#pragma unroll
    for (int i = 0; i < 8; i++) acc[i] = {0.f, 0.f, 0.f, 0.f};

    const __bf16* xb = xcl + (size_t)b * H * W * C;

    // two gather sets + two B-frag sets (rule #20: named, static)
    uint4 uA0, uA1, uA2, uA3, uB0, uB1, uB2, uB3;
    float4 pwA, pwB;
    bf16x8 Ba[8], Bb[8];

    auto LOADGA = [&](int ls) {
        int k = ls / CHW, chl = ls - k * CHW;
        int4 pi = pki[k * 16 + row];        // 4 lanes same addr -> broadcast
        pwA = pkw[k * 16 + row];
        int cb = (wave * CHW + chl) * 32 + kg * 8;
        uA0 = *reinterpret_cast<const uint4*>(xb + pi.x + cb);
        uA1 = *reinterpret_cast<const uint4*>(xb + pi.y + cb);
        uA2 = *reinterpret_cast<const uint4*>(xb + pi.z + cb);
        uA3 = *reinterpret_cast<const uint4*>(xb + pi.w + cb);
    };
    auto LOADGB = [&](int ls) {
        int k = ls / CHW, chl = ls - k * CHW;
        int4 pi = pki[k * 16 + row];
        pwB = pkw[k * 16 + row];
        int cb = (wave * CHW + chl) * 32 + kg * 8;
        uB0 = *reinterpret_cast<const uint4*>(xb + pi.x + cb);
        uB1 = *reinterpret_cast<const uint4*>(xb + pi.y + cb);
        uB2 = *reinterpret_cast<const uint4*>(xb + pi.z + cb);
        uB3 = *reinterpret_cast<const uint4*>(xb + pi.w + cb);
    };
    auto LOADBA = [&](int ls) {
        int k = ls / CHW, chl = ls - k * CHW;
        int sg = k * NCH + wave * CHW + chl;
        const __bf16* wbc = wkp + (size_t)sg * 4096 + lane * 8;
#pragma unroll
        for (int ot = 0; ot < 8; ot++)
            Ba[ot] = *reinterpret_cast<const bf16x8*>(wbc + ot * 512);
    };
    auto LOADBB = [&](int ls) {
        int k = ls / CHW, chl = ls - k * CHW;
        int sg = k * NCH + wave * CHW + chl;
        const __bf16* wbc = wkp + (size_t)sg * 4096 + lane * 8;
#pragma unroll
        for (int ot = 0; ot < 8; ot++)
            Bb[ot] = *reinterpret_cast<const bf16x8*>(wbc + ot * 512);
    };
    auto ABLEND = [&](const uint4& a0, const uint4& a1, const uint4& a2, const uint4& a3,
                      const float4& pwc) -> bf16x8 {
        bf16x8 v00 = __builtin_bit_cast(bf16x8, a0);
        bf16x8 v01 = __builtin_bit_cast(bf16x8, a1);
        bf16x8 v10 = __builtin_bit_cast(bf16x8, a2);
        bf16x8 v11 = __builtin_bit_cast(bf16x8, a3);
        bf16x8 rg;
#pragma unroll
        for (int j = 0; j < 8; j++) {
            float sv = pwc.x * (float)v00[j] + pwc.y * (float)v01[j]
                     + pwc.z * (float)v10[j] + pwc.w * (float)v11[j];
            rg[j] = (__bf16)sv;
        }
        return rg;
    };

    // prologue: B before g per set (waiting g(s) also covers B(s))
    LOADBA(0); LOADGA(0);
    LOADBB(1); LOADGB(1);
    for (int s = 0; s < NSW; s += 2) {
        {   // even step: consume set A; refill A for s+2 (issued after MFMA reads Ba)
            bf16x8 a = ABLEND(uA0, uA1, uA2, uA3, pwA);
#pragma unroll
            for (int ot = 0; ot < 8; ot++)
                acc[ot] = __builtin_amdgcn_mfma_f32_16x16x32_bf16(a, Ba[ot], acc[ot], 0, 0, 0);
            if (s + 2 < NSW) { LOADBA(s + 2); LOADGA(s + 2); }
        }
        {   // odd step: consume set B; refill B for s+3
            bf16x8 a = ABLEND(uB0, uB1, uB2, uB3, pwB);
#pragma unroll
            for (int ot = 0; ot < 8; ot++)
                acc[ot] = __builtin_amdgcn_mfma_f32_16x16x32_bf16(a, Bb[ot], acc[ot], 0, 0, 0);
            if (s + 3 < NSW) { LOADBB(s + 3); LOADGB(s + 3); }
        }
    }

    // split-K reduce: waves 1..KS-1 park partials in LDS (alias, post-barrier), wave 0 sums
    __syncthreads();
    if (wave > 0) {
        float* rd = reinterpret_cast<float*>(smem) + (wave - 1) * 2304;  // 9216B slice
#pragma unroll
        for (int ot = 0; ot < 8; ot++)
            *reinterpret_cast<f32x4*>(rd + lane * 36 + ot * 4) = acc[ot];
    }
    __syncthreads();
    if (wave == 0) {
        for (int s = 0; s < KS - 1; s++) {
            float* rd = reinterpret_cast<float*>(smem) + s * 2304;
#pragma unroll
            for (int ot = 0; ot < 8; ot++) {
                f32x4 v = *reinterpret_cast<const f32x4*>(rd + lane * 36 + ot * 4);
                acc[ot] += v;
            }
        }
        // epilogue, D map: o = ot*16 + row, pos = kg*4 + j
        if (CF_OUT) {
            float* ob = outcf + (size_t)b * OO * H * W + (size_t)h * W + wt * 16;
#pragma unroll
            for (int ot = 0; ot < 8; ot++) {
                int o = ot * 16 + row;
                float s = sc[o], hh = sh[o];
#pragma unroll
                for (int j = 0; j < 4; j++) {
                    float y = fmaxf(acc[ot][j] * s + hh, 0.f);
                    ob[(size_t)o * H * W + kg * 4 + j] = y;
                }
            }
        } else {
            __bf16* ob = outcl + (((size_t)b * H + h) * W + wt * 16) * OO;
#pragma unroll
            for (int ot = 0; ot < 8; ot++) {
                int o = ot * 16 + row;
                float s = sc[o], hh = sh[o];
#pragma unroll
                for (int j = 0; j < 4; j++) {
                    float y = fmaxf(acc[ot][j] * s + hh, 0.f);
                    ob[(size_t)(kg * 4 + j) * OO + o] = (__bf16)y;
                }
            }
        }
    }
}

// ---------- bilinear x2 depthwise transposed conv + residual ----------
__global__ __launch_bounds__(256) void upsample_cl_kernel(
    const __bf16* __restrict__ h1cl,  // [B][HA][WA][O] bf16
    const float* __restrict__ prex,   // [B][O][HC][WC] fp32
    const float* __restrict__ upwt,   // [16][O]
    __bf16* __restrict__ zcl)         // [B][HC][WC][O] bf16
{
    int idx = blockIdx.x * blockDim.x + threadIdx.x;
    int x  = idx & (WC - 1);
    int y  = (idx >> 8) & (HC - 1);
    int cg = (idx >> 15) & 15;
    int b  = idx >> 19;

    int sy0, iy0, sy1, iy1, sx0, ix0, sx1, ix1;
    if (y & 1) { sy0 = (y - 1) >> 1; iy0 = 2; sy1 = sy0 + 1; iy1 = 0; }
    else       { sy0 = (y >> 1) - 1; iy0 = 3; sy1 = sy0 + 1; iy1 = 1; }
    if (x & 1) { sx0 = (x - 1) >> 1; ix0 = 2; sx1 = sx0 + 1; ix1 = 0; }
    else       { sx0 = (x >> 1) - 1; ix0 = 3; sx1 = sx0 + 1; ix1 = 1; }

    int c0 = cg * 8;
    float acc[8];
    const float* pp = prex + ((size_t)b * OO + c0) * (HC * WC) + (size_t)y * WC + x;
#pragma unroll
    for (int j = 0; j < 8; j++) acc[j] = pp[(size_t)j * HC * WC];

    bool y0v = sy0 >= 0, y1v = sy1 < HA;
    bool x0v = sx0 >= 0, x1v = sx1 < WA;
    const __bf16* hb = h1cl + (size_t)b * HA * WA * OO + c0;

    auto tap = [&](int sy, int sx, int wi) {
        uint4 u = *reinterpret_cast<const uint4*>(hb + ((size_t)sy * WA + sx) * OO);
        bf16x8 v = __builtin_bit_cast(bf16x8, u);
        const float* wp = upwt + wi * OO + c0;
#pragma unroll
        for (int j = 0; j < 8; j++) acc[j] += (float)v[j] * wp[j];
    };
    if (y0v && x0v) tap(sy0, sx0, iy0 * 4 + ix0);
    if (y0v && x1v) tap(sy0, sx1, iy0 * 4 + ix1);
    if (y1v && x0v) tap(sy1, sx0, iy1 * 4 + ix0);
    if (y1v && x1v) tap(sy1, sx1, iy1 * 4 + ix1);

    bf16x8 r;
#pragma unroll
    for (int j = 0; j < 8; j++) r[j] = (__bf16)acc[j];
    *reinterpret_cast<bf16x8*>(zcl + (((size_t)b * HC + y) * WC + x) * OO + c0) = r;
}

// ---------------- launch ----------------
extern "C" void kernel_launch(void* const* d_in, const int* in_sizes, int n_in,
                              void* d_out, int out_size, void* d_ws, size_t ws_size,
                              hipStream_t stream) {
    (void)in_sizes; (void)n_in; (void)out_size; (void)ws_size;
    const float* x      = (const float*)d_in[0];
    const float* pre_x  = (const float*)d_in[1];
    const float* pwom   = (const float*)d_in[2];
    const float* pbom   = (const float*)d_in[3];
    const float* pw     = (const float*)d_in[4];
    const float* pb     = (const float*)d_in[5];
    const float* pgam   = (const float*)d_in[6];
    const float* pbet   = (const float*)d_in[7];
    const float* pmea   = (const float*)d_in[8];
    const float* pvar   = (const float*)d_in[9];
    const float* nwom   = (const float*)d_in[10];
    const float* nbom   = (const float*)d_in[11];
    const float* nw     = (const float*)d_in[12];
    const float* nb     = (const float*)d_in[13];
    const float* ngam   = (const float*)d_in[14];
    const float* nbet   = (const float*)d_in[15];
    const float* nmea   = (const float*)d_in[16];
    const float* nvar   = (const float*)d_in[17];
    const float* upw    = (const float*)d_in[18];
    float* out = (float*)d_out;

    char* wsb = (char*)d_ws;
    __bf16* xclA  = (__bf16*)(wsb + 0);          //  8,388,608 B
    __bf16* h1cl  = (__bf16*)(wsb + 8388608);    //  4,194,304
    __bf16* zcl   = (__bf16*)(wsb + 12582912);   // 16,777,216
    float*  omA   = (float*) (wsb + 29360128);   //  2,097,152
    float*  omC   = (float*) (wsb + 31457280);   //  8,388,608
    __bf16* wkAp  = (__bf16*)(wsb + 39845888);   //    589,824
    __bf16* wkCp  = (__bf16*)(wsb + 40435712);   //    294,912
    __bf16* womAp = (__bf16*)(wsb + 40730624);   //    147,456
    __bf16* womCp = (__bf16*)(wsb + 40878080);   //     73,728
    float*  upwt  = (float*) (wsb + 40951808);   //      8,192
    float*  scA   = (float*) (wsb + 40960000);
    float*  shA   = (float*) (wsb + 40960512);
    float*  scC   = (float*) (wsb + 40961024);
    float*  shC   = (float*) (wsb + 40961536);   // end ~41.0 MB

    // prepacks
    pack_w_kernel<<<1152, 256, 0, stream>>>(pw, wkAp, CA, 8, 128);
    pack_w_kernel<<<576, 256, 0, stream>>>(nw, wkCp, CC, 8, 128);
    pack_w_kernel<<<288, 256, 0, stream>>>(pwom, womAp, CA, 2, 27);
    pack_w_kernel<<<144, 256, 0, stream>>>(nwom, womCp, CC, 2, 27);
    bn_prepack_kernel<<<1, 128, 0, stream>>>(pgam, pbet, pmea, pvar, pb, scA, shA);
    bn_prepack_kernel<<<1, 128, 0, stream>>>(ngam, nbet, nmea, nvar, nb, scC, shC);
    pack_upw_kernel<<<8, 256, 0, stream>>>(upw, upwt);
    to_cl_kernel<CA, HA*WA><<<BN2 * (CA/32) * (HA*WA/64), 256, 0, stream>>>(x, xclA);

    // stage A
    om_mfma_kernel<CA, HA, WA><<<BN2 * HA * (WA/64), 256, 0, stream>>>(xclA, womAp, pbom, omA);
    dcn_mfma8_kernel<CA, HA, WA, 4, false><<<BN2 * HA * (WA/16), 256, 0, stream>>>(
        xclA, omA, wkAp, scA, shA, nullptr, h1cl);

    // upsample + residual
    upsample_cl_kernel<<<(BN2 * 16 * HC * WC) / 256, 256, 0, stream>>>(h1cl, pre_x, upwt, zcl);

    // stage C — KS=1: single autonomous wave per block
    om_mfma_kernel<CC, HC, WC><<<BN2 * HC * (WC/64), 256, 0, stream>>>(zcl, womCp, nbom, omC);
    dcn_mfma8_kernel<CC, HC, WC, 1, true><<<BN2 * HC * (WC/16), 64, 0, stream>>>(
        zcl, omC, wkCp, scC, shC, out, nullptr);
}

// Round 16
// 184.694 us; speedup vs baseline: 1.2952x; 1.2952x over previous
//
#include <hip/hip_runtime.h>
#include <hip/hip_bf16.h>
#include <math.h>

typedef __bf16 bf16x8 __attribute__((ext_vector_type(8)));
typedef float  f32x4  __attribute__((ext_vector_type(4)));

static constexpr int BN2 = 2;
static constexpr int CA = 256, HA = 64, WA = 128;   // stage A input
static constexpr int OO = 128;                      // output channels
static constexpr int HC = 128, WC = 256, CC = 128;  // stage C

// ---------- pack weights into MFMA B-fragment layout: [9][C/32][OT][64][8] bf16 ----------
__global__ void pack_w_kernel(const float* __restrict__ w, __bf16* __restrict__ out,
                              int Cin, int OT, int Oreal) {
    int NCH = Cin / 32;
    int idx = blockIdx.x * blockDim.x + threadIdx.x;
    int total = 9 * NCH * OT * 512;
    if (idx >= total) return;
    int j    = idx & 7;
    int lane = (idx >> 3) & 63;
    int ot   = (idx >> 9) % OT;
    int rest = (idx >> 9) / OT;
    int ch = rest % NCH;
    int k  = rest / NCH;
    int o = ot * 16 + (lane & 15);
    int c = ch * 32 + (lane >> 4) * 8 + j;
    float v = (o < Oreal) ? w[((size_t)o * Cin + c) * 9 + k] : 0.f;
    out[idx] = (__bf16)v;
}

// ---------- NCHW fp32 -> NHWC bf16 (LDS tile transpose) ----------
template<int C, int HW>
__global__ __launch_bounds__(256) void to_cl_kernel(const float* __restrict__ x,
                                                    __bf16* __restrict__ xcl) {
    constexpr int NCB = C / 32;
    constexpr int NPB = HW / 64;
    int blk = blockIdx.x;
    int pblk = blk % NPB;
    int cblk = (blk / NPB) % NCB;
    int b = blk / (NPB * NCB);
    int t = threadIdx.x;
    __shared__ float st[32][65];
    int r = t >> 6, q = t & 63;
#pragma unroll
    for (int i = 0; i < 8; i++) {
        int c = cblk * 32 + i * 4 + r;
        st[i * 4 + r][q] = x[((size_t)b * C + c) * HW + pblk * 64 + q];
    }
    __syncthreads();
    int p = t >> 2, cq = t & 3;
    bf16x8 v;
#pragma unroll
    for (int j = 0; j < 8; j++) v[j] = (__bf16)st[cq * 8 + j][p];
    *reinterpret_cast<bf16x8*>(xcl + ((size_t)b * HW + pblk * 64 + p) * C + cblk * 32 + cq * 8) = v;
}

// ---------- fold bias+BN into per-o scale/shift ----------
__global__ void bn_prepack_kernel(const float* __restrict__ g,  const float* __restrict__ be,
                                  const float* __restrict__ mu, const float* __restrict__ va,
                                  const float* __restrict__ bi,
                                  float* __restrict__ sc, float* __restrict__ sh) {
    int i = blockIdx.x * blockDim.x + threadIdx.x;
    if (i >= OO) return;
    float s = g[i] * rsqrtf(va[i] + 1e-5f);
    sc[i] = s;
    sh[i] = (bi[i] - mu[i]) * s + be[i];
}

// ---------- upw[O][4][4] -> upwt[16][O] ----------
__global__ void pack_upw_kernel(const float* __restrict__ upw, float* __restrict__ upwt) {
    int idx = blockIdx.x * blockDim.x + threadIdx.x;
    if (idx >= 16 * OO) return;
    int i = idx >> 7;
    int o = idx & 127;
    upwt[i * OO + o] = upw[o * 16 + i];
}

// ---------- om-conv as MFMA, bf16 window (WS=198) — r13-proven ----------
template<int C, int H, int W>
__global__ __launch_bounds__(256) void om_mfma_kernel(
    const __bf16* __restrict__ xcl,   // [B][H][W][C]
    const __bf16* __restrict__ womp,  // [9][C/32][2][64][8] bf16
    const float* __restrict__ bom,    // [27]
    float* __restrict__ omcl)         // [B][H][W][32]
{
    constexpr int NCH = C / 32;
    constexpr int WS = 198;
    const int nwt = W / 64;
    int wt = blockIdx.x % nwt;
    int h  = (blockIdx.x / nwt) % H;
    int b  = blockIdx.x / (nwt * H);
    int t = threadIdx.x;
    int wave = t >> 6, lane = t & 63;
    int row = lane & 15, kg = lane >> 4;

    __shared__ __bf16 win[32 * WS];   // 12672 B

    f32x4 acc0 = {0.f, 0.f, 0.f, 0.f};
    f32x4 acc1 = {0.f, 0.f, 0.f, 0.f};
    const __bf16* xb = xcl + (size_t)b * H * W * C;

    for (int ch = 0; ch < NCH; ch++) {
        for (int i = 0; i < 4; i++) {
            int idx = i * 256 + t;
            if (idx < 792) {
                int cq  = idx & 3;
                int pix = idx >> 2;
                int ry = pix / 66, rx = pix % 66;
                int y = h + ry - 1, xx = wt * 64 + rx - 1;
                bool valid = (y >= 0) && (y < H) && (xx >= 0) && (xx < W);
                int yc = min(max(y, 0), H - 1), xc = min(max(xx, 0), W - 1);
                uint4 u = *reinterpret_cast<const uint4*>(
                    xb + ((size_t)yc * W + xc) * C + ch * 32 + cq * 8);
                if (!valid) { u.x = 0; u.y = 0; u.z = 0; u.w = 0; }
                bf16x8 v = __builtin_bit_cast(bf16x8, u);
#pragma unroll
                for (int j = 0; j < 8; j++)
                    win[(cq * 8 + j) * WS + pix] = v[j];
            }
        }
        __syncthreads();
#pragma unroll
        for (int k = 0; k < 9; k++) {
            int off = (k / 3) * 66 + (k % 3) + wave * 16 + row;
            bf16x8 a;
#pragma unroll
            for (int j = 0; j < 8; j++)
                a[j] = win[(kg * 8 + j) * WS + off];
            const __bf16* wbc = womp + ((size_t)k * NCH + ch) * 1024 + lane * 8;
            bf16x8 b0 = *reinterpret_cast<const bf16x8*>(wbc);
            bf16x8 b1 = *reinterpret_cast<const bf16x8*>(wbc + 512);
            acc0 = __builtin_amdgcn_mfma_f32_16x16x32_bf16(a, b0, acc0, 0, 0, 0);
            acc1 = __builtin_amdgcn_mfma_f32_16x16x32_bf16(a, b1, acc1, 0, 0, 0);
        }
        __syncthreads();
    }

    float* ob = omcl + (((size_t)b * H + h) * W + wt * 64 + wave * 16 + kg * 4) * 32;
    float bb0 = bom[row];
#pragma unroll
    for (int j = 0; j < 4; j++)
        ob[(size_t)j * 32 + row] = acc0[j] + bb0;
    if (row < 11) {
        float bb1 = bom[16 + row];
#pragma unroll
        for (int j = 0; j < 4; j++)
            ob[(size_t)j * 32 + 16 + row] = acc1[j] + bb1;
    }
}

// ---------- DCN v6 (r11/r13/r14-proven): 16-pos tiles + split-K + B-prefetch ----------
template<int C, int H, int W, int KS, bool CF_OUT>
__global__ __launch_bounds__(64 * KS) void dcn_mfma6_kernel(
    const __bf16* __restrict__ xcl,  // [B][H][W][C]
    const float* __restrict__ omcl,  // [B][H][W][32]
    const __bf16* __restrict__ wkp,  // [9][C/32][8][64][8] bf16 (pack_w)
    const float* __restrict__ sc, const float* __restrict__ sh,
    float* __restrict__ outcf,       // CF_OUT: [B][O][H][W] fp32
    __bf16* __restrict__ outcl)      // else:   [B][H][W][O] bf16
{
    constexpr int NCH = C / 32;
    constexpr int CHW = NCH / KS;
    constexpr int NSW = 9 * CHW;
    static_assert(NSW % 2 == 0, "unroll-by-2 needs even NSW");
    constexpr int MAIN = 4608 + KS * 2560;
    constexpr int RED  = (KS - 1) * 9216;
    constexpr int SMEM = MAIN > RED ? MAIN : RED;

    const int nwt = W / 16;
    int wt = blockIdx.x % nwt;
    int h  = (blockIdx.x / nwt) % H;
    int b  = blockIdx.x / (nwt * H);
    int t = threadIdx.x;
    int wave = t >> 6, lane = t & 63;
    int row = lane & 15, kg = lane >> 4;
    int pos16 = lane >> 2, cq = lane & 3;

    __shared__ __align__(16) char smem[SMEM];
    int4*   pki  = reinterpret_cast<int4*>(smem);            // [144]
    float4* pkw  = reinterpret_cast<float4*>(smem + 2304);   // [144]
    __bf16* sbuf = reinterpret_cast<__bf16*>(smem + 4608);   // [KS][2][16*40]

    const float* omb = omcl + (((size_t)b * H + h) * W + wt * 16) * 32;
    for (int idx = t; idx < 144; idx += 64 * KS) {
        int p = idx & 15;
        int k = idx >> 4;
        float o1 = omb[p * 32 + k];
        float o2 = omb[p * 32 + 9 + k];
        float mm = omb[p * 32 + 18 + k];
        mm = 1.f / (1.f + expf(-mm));
        float py = o1 + (float)(h + k / 3 - 1);
        float px = o2 + (float)(wt * 16 + p + k % 3 - 1);
        float y0f = floorf(py), x0f = floorf(px);
        float wy = py - y0f, wx = px - x0f;
        int y0 = (int)y0f, x0 = (int)x0f;
        bool y0v = (y0 >= 0) && (y0 < H);
        bool y1v = (y0 + 1 >= 0) && (y0 + 1 < H);
        bool x0v = (x0 >= 0) && (x0 < W);
        bool x1v = (x0 + 1 >= 0) && (x0 + 1 < W);
        int y0c = min(max(y0, 0), H - 1) * W;
        int y1c = min(max(y0 + 1, 0), H - 1) * W;
        int x0c = min(max(x0, 0), W - 1);
        int x1c = min(max(x0 + 1, 0), W - 1);
        int4 pi;
        pi.x = (y0c + x0c) * C; pi.y = (y0c + x1c) * C;
        pi.z = (y1c + x0c) * C; pi.w = (y1c + x1c) * C;
        float4 pw;
        pw.x = (y0v && x0v) ? (1.f - wy) * (1.f - wx) * mm : 0.f;
        pw.y = (y0v && x1v) ? (1.f - wy) * wx * mm : 0.f;
        pw.z = (y1v && x0v) ? wy * (1.f - wx) * mm : 0.f;
        pw.w = (y1v && x1v) ? wy * wx * mm : 0.f;
        pki[idx] = pi;
        pkw[idx] = pw;
    }
    __syncthreads();

    f32x4 acc[8];
#pragma unroll
    for (int i = 0; i < 8; i++) acc[i] = {0.f, 0.f, 0.f, 0.f};

    const __bf16* xb = xcl + (size_t)b * H * W * C;
    __bf16* sb = sbuf + wave * 1280;
    __bf16* wp0 = sb + pos16 * 40 + cq * 8;
    const __bf16* rp0 = sb + row * 40 + kg * 8;

    uint4 u00, u01, u10, u11;
    float4 pwc;
    bf16x8 Ba[8], Bb[8];

    auto LOADG = [&](int ls) {
        int k = ls / CHW, chl = ls - k * CHW;
        int4 pi = pki[k * 16 + pos16];
        pwc = pkw[k * 16 + pos16];
        int cb = (wave * CHW + chl) * 32 + cq * 8;
        u00 = *reinterpret_cast<const uint4*>(xb + pi.x + cb);
        u01 = *reinterpret_cast<const uint4*>(xb + pi.y + cb);
        u10 = *reinterpret_cast<const uint4*>(xb + pi.z + cb);
        u11 = *reinterpret_cast<const uint4*>(xb + pi.w + cb);
    };
    auto LOADBA = [&](int ls) {
        int k = ls / CHW, chl = ls - k * CHW;
        int sg = k * NCH + wave * CHW + chl;
        const __bf16* wbc = wkp + (size_t)sg * 4096 + lane * 8;
#pragma unroll
        for (int ot = 0; ot < 8; ot++)
            Ba[ot] = *reinterpret_cast<const bf16x8*>(wbc + ot * 512);
    };
    auto LOADBB = [&](int ls) {
        int k = ls / CHW, chl = ls - k * CHW;
        int sg = k * NCH + wave * CHW + chl;
        const __bf16* wbc = wkp + (size_t)sg * 4096 + lane * 8;
#pragma unroll
        for (int ot = 0; ot < 8; ot++)
            Bb[ot] = *reinterpret_cast<const bf16x8*>(wbc + ot * 512);
    };
    auto BLEND = [&](int bufoff) {
        bf16x8 v00 = __builtin_bit_cast(bf16x8, u00);
        bf16x8 v01 = __builtin_bit_cast(bf16x8, u01);
        bf16x8 v10 = __builtin_bit_cast(bf16x8, u10);
        bf16x8 v11 = __builtin_bit_cast(bf16x8, u11);
        bf16x8 rg;
#pragma unroll
        for (int j = 0; j < 8; j++) {
            float sv = pwc.x * (float)v00[j] + pwc.y * (float)v01[j]
                     + pwc.z * (float)v10[j] + pwc.w * (float)v11[j];
            rg[j] = (__bf16)sv;
        }
        *reinterpret_cast<bf16x8*>(wp0 + bufoff) = rg;
    };
    auto MFMAA = [&](int bufoff) {
        bf16x8 a = *reinterpret_cast<const bf16x8*>(rp0 + bufoff);
#pragma unroll
        for (int ot = 0; ot < 8; ot++)
            acc[ot] = __builtin_amdgcn_mfma_f32_16x16x32_bf16(a, Ba[ot], acc[ot], 0, 0, 0);
    };
    auto MFMAB = [&](int bufoff) {
        bf16x8 a = *reinterpret_cast<const bf16x8*>(rp0 + bufoff);
#pragma unroll
        for (int ot = 0; ot < 8; ot++)
            acc[ot] = __builtin_amdgcn_mfma_f32_16x16x32_bf16(a, Bb[ot], acc[ot], 0, 0, 0);
    };

    LOADBA(0);
    LOADG(0);
    for (int s = 0; s < NSW; s += 2) {
        BLEND(0);
        LOADBB(s + 1);
        LOADG(s + 1);
        MFMAA(0);
        BLEND(640);
        if (s + 2 < NSW) { LOADBA(s + 2); LOADG(s + 2); }
        MFMAB(640);
    }

    __syncthreads();
    if (wave > 0) {
        float* rd = reinterpret_cast<float*>(smem) + (wave - 1) * 2304;
#pragma unroll
        for (int ot = 0; ot < 8; ot++)
            *reinterpret_cast<f32x4*>(rd + lane * 36 + ot * 4) = acc[ot];
    }
    __syncthreads();
    if (wave == 0) {
        for (int s = 0; s < KS - 1; s++) {
            float* rd = reinterpret_cast<float*>(smem) + s * 2304;
#pragma unroll
            for (int ot = 0; ot < 8; ot++) {
                f32x4 v = *reinterpret_cast<const f32x4*>(rd + lane * 36 + ot * 4);
                acc[ot] += v;
            }
        }
        if (CF_OUT) {
            float* ob = outcf + (size_t)b * OO * H * W + (size_t)h * W + wt * 16;
#pragma unroll
            for (int ot = 0; ot < 8; ot++) {
                int o = ot * 16 + row;
                float s = sc[o], hh = sh[o];
#pragma unroll
                for (int j = 0; j < 4; j++) {
                    float y = fmaxf(acc[ot][j] * s + hh, 0.f);
                    ob[(size_t)o * H * W + kg * 4 + j] = y;
                }
            }
        } else {
            __bf16* ob = outcl + (((size_t)b * H + h) * W + wt * 16) * OO;
#pragma unroll
            for (int ot = 0; ot < 8; ot++) {
                int o = ot * 16 + row;
                float s = sc[o], hh = sh[o];
#pragma unroll
                for (int j = 0; j < 4; j++) {
                    float y = fmaxf(acc[ot][j] * s + hh, 0.f);
                    ob[(size_t)(kg * 4 + j) * OO + o] = (__bf16)y;
                }
            }
        }
    }
}

// ---------- DCN v9: 4 AUTONOMOUS waves per 256-thd block (beats the WG-slot cap) ----------
// Each wave = one 16-pos tile, full channel range (KS=1 semantics), own LDS slice,
// ZERO barriers (per-wave DS ordering). Data path byte-identical to v6.
template<int C, int H, int W, bool CF_OUT>
__global__ __launch_bounds__(256) void dcn_mfma9_kernel(
    const __bf16* __restrict__ xcl,  // [B][H][W][C]
    const float* __restrict__ omcl,  // [B][H][W][32]
    const __bf16* __restrict__ wkp,  // [9][C/32][8][64][8] bf16 (pack_w)
    const float* __restrict__ sc, const float* __restrict__ sh,
    float* __restrict__ outcf,       // CF_OUT: [B][O][H][W] fp32
    __bf16* __restrict__ outcl)      // else:   [B][H][W][O] bf16
{
    constexpr int NCH = C / 32;
    constexpr int NSW = 9 * NCH;     // 36 for C=128
    static_assert(NSW % 2 == 0, "unroll-by-2 needs even NSW");

    int t = threadIdx.x;
    int wave = t >> 6, lane = t & 63;
    int row = lane & 15, kg = lane >> 4;
    int pos16 = lane >> 2, cq = lane & 3;

    __shared__ __align__(16) char smem[4 * 7168];    // per-wave: pk 4608 + sbuf 2560
    char* ws = smem + wave * 7168;
    int4*   pki = reinterpret_cast<int4*>(ws);           // [144]
    float4* pkw = reinterpret_cast<float4*>(ws + 2304);  // [144]
    __bf16* sb  = reinterpret_cast<__bf16*>(ws + 4608);  // [2][640]

    const int nwt = W / 16;
    int tile = blockIdx.x * 4 + wave;
    int wt = tile % nwt;
    int h  = (tile / nwt) % H;
    int b  = tile / (nwt * H);

    // per-wave precompute (same-wave DS ordering -> no barrier)
    const float* omb = omcl + (((size_t)b * H + h) * W + wt * 16) * 32;
    for (int idx = lane; idx < 144; idx += 64) {
        int p = idx & 15;
        int k = idx >> 4;
        float o1 = omb[p * 32 + k];
        float o2 = omb[p * 32 + 9 + k];
        float mm = omb[p * 32 + 18 + k];
        mm = 1.f / (1.f + expf(-mm));
        float py = o1 + (float)(h + k / 3 - 1);
        float px = o2 + (float)(wt * 16 + p + k % 3 - 1);
        float y0f = floorf(py), x0f = floorf(px);
        float wy = py - y0f, wx = px - x0f;
        int y0 = (int)y0f, x0 = (int)x0f;
        bool y0v = (y0 >= 0) && (y0 < H);
        bool y1v = (y0 + 1 >= 0) && (y0 + 1 < H);
        bool x0v = (x0 >= 0) && (x0 < W);
        bool x1v = (x0 + 1 >= 0) && (x0 + 1 < W);
        int y0c = min(max(y0, 0), H - 1) * W;
        int y1c = min(max(y0 + 1, 0), H - 1) * W;
        int x0c = min(max(x0, 0), W - 1);
        int x1c = min(max(x0 + 1, 0), W - 1);
        int4 pi;
        pi.x = (y0c + x0c) * C; pi.y = (y0c + x1c) * C;
        pi.z = (y1c + x0c) * C; pi.w = (y1c + x1c) * C;
        float4 pw;
        pw.x = (y0v && x0v) ? (1.f - wy) * (1.f - wx) * mm : 0.f;
        pw.y = (y0v && x1v) ? (1.f - wy) * wx * mm : 0.f;
        pw.z = (y1v && x0v) ? wy * (1.f - wx) * mm : 0.f;
        pw.w = (y1v && x1v) ? wy * wx * mm : 0.f;
        pki[idx] = pi;
        pkw[idx] = pw;
    }

    f32x4 acc[8];
#pragma unroll
    for (int i = 0; i < 8; i++) acc[i] = {0.f, 0.f, 0.f, 0.f};

    const __bf16* xb = xcl + (size_t)b * H * W * C;
    __bf16* wp0 = sb + pos16 * 40 + cq * 8;
    const __bf16* rp0 = sb + row * 40 + kg * 8;

    uint4 u00, u01, u10, u11;
    float4 pwc;
    bf16x8 Ba[8], Bb[8];

    auto LOADG = [&](int ls) {
        int k = ls / NCH, chl = ls - k * NCH;
        int4 pi = pki[k * 16 + pos16];
        pwc = pkw[k * 16 + pos16];
        int cb = chl * 32 + cq * 8;
        u00 = *reinterpret_cast<const uint4*>(xb + pi.x + cb);
        u01 = *reinterpret_cast<const uint4*>(xb + pi.y + cb);
        u10 = *reinterpret_cast<const uint4*>(xb + pi.z + cb);
        u11 = *reinterpret_cast<const uint4*>(xb + pi.w + cb);
    };
    auto LOADBA = [&](int ls) {
        const __bf16* wbc = wkp + (size_t)ls * 4096 + lane * 8;   // sg == ls (KS=1)
#pragma unroll
        for (int ot = 0; ot < 8; ot++)
            Ba[ot] = *reinterpret_cast<const bf16x8*>(wbc + ot * 512);
    };
    auto LOADBB = [&](int ls) {
        const __bf16* wbc = wkp + (size_t)ls * 4096 + lane * 8;
#pragma unroll
        for (int ot = 0; ot < 8; ot++)
            Bb[ot] = *reinterpret_cast<const bf16x8*>(wbc + ot * 512);
    };
    auto BLEND = [&](int bufoff) {
        bf16x8 v00 = __builtin_bit_cast(bf16x8, u00);
        bf16x8 v01 = __builtin_bit_cast(bf16x8, u01);
        bf16x8 v10 = __builtin_bit_cast(bf16x8, u10);
        bf16x8 v11 = __builtin_bit_cast(bf16x8, u11);
        bf16x8 rg;
#pragma unroll
        for (int j = 0; j < 8; j++) {
            float sv = pwc.x * (float)v00[j] + pwc.y * (float)v01[j]
                     + pwc.z * (float)v10[j] + pwc.w * (float)v11[j];
            rg[j] = (__bf16)sv;
        }
        *reinterpret_cast<bf16x8*>(wp0 + bufoff) = rg;
    };
    auto MFMAA = [&](int bufoff) {
        bf16x8 a = *reinterpret_cast<const bf16x8*>(rp0 + bufoff);
#pragma unroll
        for (int ot = 0; ot < 8; ot++)
            acc[ot] = __builtin_amdgcn_mfma_f32_16x16x32_bf16(a, Ba[ot], acc[ot], 0, 0, 0);
    };
    auto MFMAB = [&](int bufoff) {
        bf16x8 a = *reinterpret_cast<const bf16x8*>(rp0 + bufoff);
#pragma unroll
        for (int ot = 0; ot < 8; ot++)
            acc[ot] = __builtin_amdgcn_mfma_f32_16x16x32_bf16(a, Bb[ot], acc[ot], 0, 0, 0);
    };

    LOADBA(0);
    LOADG(0);
    for (int s = 0; s < NSW; s += 2) {
        BLEND(0);
        LOADBB(s + 1);
        LOADG(s + 1);
        MFMAA(0);
        BLEND(640);
        if (s + 2 < NSW) { LOADBA(s + 2); LOADG(s + 2); }
        MFMAB(640);
    }

    // epilogue (every wave its own tile), D map: o = ot*16+row, pos = kg*4+j
    if (CF_OUT) {
        float* ob = outcf + (size_t)b * OO * H * W + (size_t)h * W + wt * 16;
#pragma unroll
        for (int ot = 0; ot < 8; ot++) {
            int o = ot * 16 + row;
            float s = sc[o], hh = sh[o];
#pragma unroll
            for (int j = 0; j < 4; j++) {
                float y = fmaxf(acc[ot][j] * s + hh, 0.f);
                ob[(size_t)o * H * W + kg * 4 + j] = y;
            }
        }
    } else {
        __bf16* ob = outcl + (((size_t)b * H + h) * W + wt * 16) * OO;
#pragma unroll
        for (int ot = 0; ot < 8; ot++) {
            int o = ot * 16 + row;
            float s = sc[o], hh = sh[o];
#pragma unroll
            for (int j = 0; j < 4; j++) {
                float y = fmaxf(acc[ot][j] * s + hh, 0.f);
                ob[(size_t)(kg * 4 + j) * OO + o] = (__bf16)y;
            }
        }
    }
}

// ---------- bilinear x2 depthwise transposed conv + residual ----------
__global__ __launch_bounds__(256) void upsample_cl_kernel(
    const __bf16* __restrict__ h1cl,  // [B][HA][WA][O] bf16
    const float* __restrict__ prex,   // [B][O][HC][WC] fp32
    const float* __restrict__ upwt,   // [16][O]
    __bf16* __restrict__ zcl)         // [B][HC][WC][O] bf16
{
    int idx = blockIdx.x * blockDim.x + threadIdx.x;
    int x  = idx & (WC - 1);
    int y  = (idx >> 8) & (HC - 1);
    int cg = (idx >> 15) & 15;
    int b  = idx >> 19;

    int sy0, iy0, sy1, iy1, sx0, ix0, sx1, ix1;
    if (y & 1) { sy0 = (y - 1) >> 1; iy0 = 2; sy1 = sy0 + 1; iy1 = 0; }
    else       { sy0 = (y >> 1) - 1; iy0 = 3; sy1 = sy0 + 1; iy1 = 1; }
    if (x & 1) { sx0 = (x - 1) >> 1; ix0 = 2; sx1 = sx0 + 1; ix1 = 0; }
    else       { sx0 = (x >> 1) - 1; ix0 = 3; sx1 = sx0 + 1; ix1 = 1; }

    int c0 = cg * 8;
    float acc[8];
    const float* pp = prex + ((size_t)b * OO + c0) * (HC * WC) + (size_t)y * WC + x;
#pragma unroll
    for (int j = 0; j < 8; j++) acc[j] = pp[(size_t)j * HC * WC];

    bool y0v = sy0 >= 0, y1v = sy1 < HA;
    bool x0v = sx0 >= 0, x1v = sx1 < WA;
    const __bf16* hb = h1cl + (size_t)b * HA * WA * OO + c0;

    auto tap = [&](int sy, int sx, int wi) {
        uint4 u = *reinterpret_cast<const uint4*>(hb + ((size_t)sy * WA + sx) * OO);
        bf16x8 v = __builtin_bit_cast(bf16x8, u);
        const float* wp = upwt + wi * OO + c0;
#pragma unroll
        for (int j = 0; j < 8; j++) acc[j] += (float)v[j] * wp[j];
    };
    if (y0v && x0v) tap(sy0, sx0, iy0 * 4 + ix0);
    if (y0v && x1v) tap(sy0, sx1, iy0 * 4 + ix1);
    if (y1v && x0v) tap(sy1, sx0, iy1 * 4 + ix0);
    if (y1v && x1v) tap(sy1, sx1, iy1 * 4 + ix1);

    bf16x8 r;
#pragma unroll
    for (int j = 0; j < 8; j++) r[j] = (__bf16)acc[j];
    *reinterpret_cast<bf16x8*>(zcl + (((size_t)b * HC + y) * WC + x) * OO + c0) = r;
}

// ---------------- launch ----------------
extern "C" void kernel_launch(void* const* d_in, const int* in_sizes, int n_in,
                              void* d_out, int out_size, void* d_ws, size_t ws_size,
                              hipStream_t stream) {
    (void)in_sizes; (void)n_in; (void)out_size; (void)ws_size;
    const float* x      = (const float*)d_in[0];
    const float* pre_x  = (const float*)d_in[1];
    const float* pwom   = (const float*)d_in[2];
    const float* pbom   = (const float*)d_in[3];
    const float* pw     = (const float*)d_in[4];
    const float* pb     = (const float*)d_in[5];
    const float* pgam   = (const float*)d_in[6];
    const float* pbet   = (const float*)d_in[7];
    const float* pmea   = (const float*)d_in[8];
    const float* pvar   = (const float*)d_in[9];
    const float* nwom   = (const float*)d_in[10];
    const float* nbom   = (const float*)d_in[11];
    const float* nw     = (const float*)d_in[12];
    const float* nb     = (const float*)d_in[13];
    const float* ngam   = (const float*)d_in[14];
    const float* nbet   = (const float*)d_in[15];
    const float* nmea   = (const float*)d_in[16];
    const float* nvar   = (const float*)d_in[17];
    const float* upw    = (const float*)d_in[18];
    float* out = (float*)d_out;

    char* wsb = (char*)d_ws;
    __bf16* xclA  = (__bf16*)(wsb + 0);          //  8,388,608 B
    __bf16* h1cl  = (__bf16*)(wsb + 8388608);    //  4,194,304
    __bf16* zcl   = (__bf16*)(wsb + 12582912);   // 16,777,216
    float*  omA   = (float*) (wsb + 29360128);   //  2,097,152
    float*  omC   = (float*) (wsb + 31457280);   //  8,388,608
    __bf16* wkAp  = (__bf16*)(wsb + 39845888);   //    589,824
    __bf16* wkCp  = (__bf16*)(wsb + 40435712);   //    294,912
    __bf16* womAp = (__bf16*)(wsb + 40730624);   //    147,456
    __bf16* womCp = (__bf16*)(wsb + 40878080);   //     73,728
    float*  upwt  = (float*) (wsb + 40951808);   //      8,192
    float*  scA   = (float*) (wsb + 40960000);
    float*  shA   = (float*) (wsb + 40960512);
    float*  scC   = (float*) (wsb + 40961024);
    float*  shC   = (float*) (wsb + 40961536);   // end ~41.0 MB

    // prepacks
    pack_w_kernel<<<1152, 256, 0, stream>>>(pw, wkAp, CA, 8, 128);
    pack_w_kernel<<<576, 256, 0, stream>>>(nw, wkCp, CC, 8, 128);
    pack_w_kernel<<<288, 256, 0, stream>>>(pwom, womAp, CA, 2, 27);
    pack_w_kernel<<<144, 256, 0, stream>>>(nwom, womCp, CC, 2, 27);
    bn_prepack_kernel<<<1, 128, 0, stream>>>(pgam, pbet, pmea, pvar, pb, scA, shA);
    bn_prepack_kernel<<<1, 128, 0, stream>>>(ngam, nbet, nmea, nvar, nb, scC, shC);
    pack_upw_kernel<<<8, 256, 0, stream>>>(upw, upwt);
    to_cl_kernel<CA, HA*WA><<<BN2 * (CA/32) * (HA*WA/64), 256, 0, stream>>>(x, xclA);

    // stage A
    om_mfma_kernel<CA, HA, WA><<<BN2 * HA * (WA/64), 256, 0, stream>>>(xclA, womAp, pbom, omA);
    dcn_mfma6_kernel<CA, HA, WA, 4, false><<<BN2 * HA * (WA/16), 256, 0, stream>>>(
        xclA, omA, wkAp, scA, shA, nullptr, h1cl);

    // upsample + residual
    upsample_cl_kernel<<<(BN2 * 16 * HC * WC) / 256, 256, 0, stream>>>(h1cl, pre_x, upwt, zcl);

    // stage C — v9: 4 autonomous waves per 256-thd workgroup (4096 tiles / 4)
    om_mfma_kernel<CC, HC, WC><<<BN2 * HC * (WC/64), 256, 0, stream>>>(zcl, womCp, nbom, omC);
    dcn_mfma9_kernel<CC, HC, WC, true><<<BN2 * HC * (WC/16) / 4, 256, 0, stream>>>(
        zcl, omC, wkCp, scC, shC, out, nullptr);
}

// Round 17
// 180.948 us; speedup vs baseline: 1.3220x; 1.0207x over previous
//
#include <hip/hip_runtime.h>
#include <hip/hip_bf16.h>
#include <math.h>

typedef __bf16 bf16x8 __attribute__((ext_vector_type(8)));
typedef float  f32x4  __attribute__((ext_vector_type(4)));

static constexpr int BN2 = 2;
static constexpr int CA = 256, HA = 64, WA = 128;   // stage A input
static constexpr int OO = 128;                      // output channels
static constexpr int HC = 128, WC = 256, CC = 128;  // stage C

// ---------- pack weights into MFMA B-fragment layout: [9][C/32][OT][64][8] bf16 ----------
__global__ void pack_w_kernel(const float* __restrict__ w, __bf16* __restrict__ out,
                              int Cin, int OT, int Oreal) {
    int NCH = Cin / 32;
    int idx = blockIdx.x * blockDim.x + threadIdx.x;
    int total = 9 * NCH * OT * 512;
    if (idx >= total) return;
    int j    = idx & 7;
    int lane = (idx >> 3) & 63;
    int ot   = (idx >> 9) % OT;
    int rest = (idx >> 9) / OT;
    int ch = rest % NCH;
    int k  = rest / NCH;
    int o = ot * 16 + (lane & 15);
    int c = ch * 32 + (lane >> 4) * 8 + j;
    float v = (o < Oreal) ? w[((size_t)o * Cin + c) * 9 + k] : 0.f;
    out[idx] = (__bf16)v;
}

// ---------- NCHW fp32 -> NHWC bf16 (LDS tile transpose) ----------
template<int C, int HW>
__global__ __launch_bounds__(256) void to_cl_kernel(const float* __restrict__ x,
                                                    __bf16* __restrict__ xcl) {
    constexpr int NCB = C / 32;
    constexpr int NPB = HW / 64;
    int blk = blockIdx.x;
    int pblk = blk % NPB;
    int cblk = (blk / NPB) % NCB;
    int b = blk / (NPB * NCB);
    int t = threadIdx.x;
    __shared__ float st[32][65];
    int r = t >> 6, q = t & 63;
#pragma unroll
    for (int i = 0; i < 8; i++) {
        int c = cblk * 32 + i * 4 + r;
        st[i * 4 + r][q] = x[((size_t)b * C + c) * HW + pblk * 64 + q];
    }
    __syncthreads();
    int p = t >> 2, cq = t & 3;
    bf16x8 v;
#pragma unroll
    for (int j = 0; j < 8; j++) v[j] = (__bf16)st[cq * 8 + j][p];
    *reinterpret_cast<bf16x8*>(xcl + ((size_t)b * HW + pblk * 64 + p) * C + cblk * 32 + cq * 8) = v;
}

// ---------- fold bias+BN into per-o scale/shift ----------
__global__ void bn_prepack_kernel(const float* __restrict__ g,  const float* __restrict__ be,
                                  const float* __restrict__ mu, const float* __restrict__ va,
                                  const float* __restrict__ bi,
                                  float* __restrict__ sc, float* __restrict__ sh) {
    int i = blockIdx.x * blockDim.x + threadIdx.x;
    if (i >= OO) return;
    float s = g[i] * rsqrtf(va[i] + 1e-5f);
    sc[i] = s;
    sh[i] = (bi[i] - mu[i]) * s + be[i];
}

// ---------- upw[O][4][4] -> upwt[16][O] ----------
__global__ void pack_upw_kernel(const float* __restrict__ upw, float* __restrict__ upwt) {
    int idx = blockIdx.x * blockDim.x + threadIdx.x;
    if (idx >= 16 * OO) return;
    int i = idx >> 7;
    int o = idx & 127;
    upwt[i * OO + o] = upw[o * 16 + i];
}

// ---------- om-conv as MFMA, bf16 window (WS=198) — r13-proven ----------
template<int C, int H, int W>
__global__ __launch_bounds__(256) void om_mfma_kernel(
    const __bf16* __restrict__ xcl,   // [B][H][W][C]
    const __bf16* __restrict__ womp,  // [9][C/32][2][64][8] bf16
    const float* __restrict__ bom,    // [27]
    float* __restrict__ omcl)         // [B][H][W][32]
{
    constexpr int NCH = C / 32;
    constexpr int WS = 198;
    const int nwt = W / 64;
    int wt = blockIdx.x % nwt;
    int h  = (blockIdx.x / nwt) % H;
    int b  = blockIdx.x / (nwt * H);
    int t = threadIdx.x;
    int wave = t >> 6, lane = t & 63;
    int row = lane & 15, kg = lane >> 4;

    __shared__ __bf16 win[32 * WS];   // 12672 B

    f32x4 acc0 = {0.f, 0.f, 0.f, 0.f};
    f32x4 acc1 = {0.f, 0.f, 0.f, 0.f};
    const __bf16* xb = xcl + (size_t)b * H * W * C;

    for (int ch = 0; ch < NCH; ch++) {
        for (int i = 0; i < 4; i++) {
            int idx = i * 256 + t;
            if (idx < 792) {
                int cq  = idx & 3;
                int pix = idx >> 2;
                int ry = pix / 66, rx = pix % 66;
                int y = h + ry - 1, xx = wt * 64 + rx - 1;
                bool valid = (y >= 0) && (y < H) && (xx >= 0) && (xx < W);
                int yc = min(max(y, 0), H - 1), xc = min(max(xx, 0), W - 1);
                uint4 u = *reinterpret_cast<const uint4*>(
                    xb + ((size_t)yc * W + xc) * C + ch * 32 + cq * 8);
                if (!valid) { u.x = 0; u.y = 0; u.z = 0; u.w = 0; }
                bf16x8 v = __builtin_bit_cast(bf16x8, u);
#pragma unroll
                for (int j = 0; j < 8; j++)
                    win[(cq * 8 + j) * WS + pix] = v[j];
            }
        }
        __syncthreads();
#pragma unroll
        for (int k = 0; k < 9; k++) {
            int off = (k / 3) * 66 + (k % 3) + wave * 16 + row;
            bf16x8 a;
#pragma unroll
            for (int j = 0; j < 8; j++)
                a[j] = win[(kg * 8 + j) * WS + off];
            const __bf16* wbc = womp + ((size_t)k * NCH + ch) * 1024 + lane * 8;
            bf16x8 b0 = *reinterpret_cast<const bf16x8*>(wbc);
            bf16x8 b1 = *reinterpret_cast<const bf16x8*>(wbc + 512);
            acc0 = __builtin_amdgcn_mfma_f32_16x16x32_bf16(a, b0, acc0, 0, 0, 0);
            acc1 = __builtin_amdgcn_mfma_f32_16x16x32_bf16(a, b1, acc1, 0, 0, 0);
        }
        __syncthreads();
    }

    float* ob = omcl + (((size_t)b * H + h) * W + wt * 64 + wave * 16 + kg * 4) * 32;
    float bb0 = bom[row];
#pragma unroll
    for (int j = 0; j < 4; j++)
        ob[(size_t)j * 32 + row] = acc0[j] + bb0;
    if (row < 11) {
        float bb1 = bom[16 + row];
#pragma unroll
        for (int j = 0; j < 4; j++)
            ob[(size_t)j * 32 + 16 + row] = acc1[j] + bb1;
    }
}

// ---------- DCN v6 (r11/r13/r14-proven): 16-pos tiles + split-K + B-prefetch ----------
template<int C, int H, int W, int KS, bool CF_OUT>
__global__ __launch_bounds__(64 * KS) void dcn_mfma6_kernel(
    const __bf16* __restrict__ xcl,  // [B][H][W][C]
    const float* __restrict__ omcl,  // [B][H][W][32]
    const __bf16* __restrict__ wkp,  // [9][C/32][8][64][8] bf16 (pack_w)
    const float* __restrict__ sc, const float* __restrict__ sh,
    float* __restrict__ outcf,       // CF_OUT: [B][O][H][W] fp32
    __bf16* __restrict__ outcl)      // else:   [B][H][W][O] bf16
{
    constexpr int NCH = C / 32;
    constexpr int CHW = NCH / KS;
    constexpr int NSW = 9 * CHW;
    static_assert(NSW % 2 == 0, "unroll-by-2 needs even NSW");
    constexpr int MAIN = 4608 + KS * 2560;
    constexpr int RED  = (KS - 1) * 9216;
    constexpr int SMEM = MAIN > RED ? MAIN : RED;

    const int nwt = W / 16;
    int wt = blockIdx.x % nwt;
    int h  = (blockIdx.x / nwt) % H;
    int b  = blockIdx.x / (nwt * H);
    int t = threadIdx.x;
    int wave = t >> 6, lane = t & 63;
    int row = lane & 15, kg = lane >> 4;
    int pos16 = lane >> 2, cq = lane & 3;

    __shared__ __align__(16) char smem[SMEM];
    int4*   pki  = reinterpret_cast<int4*>(smem);            // [144]
    float4* pkw  = reinterpret_cast<float4*>(smem + 2304);   // [144]
    __bf16* sbuf = reinterpret_cast<__bf16*>(smem + 4608);   // [KS][2][16*40]

    const float* omb = omcl + (((size_t)b * H + h) * W + wt * 16) * 32;
    for (int idx = t; idx < 144; idx += 64 * KS) {
        int p = idx & 15;
        int k = idx >> 4;
        float o1 = omb[p * 32 + k];
        float o2 = omb[p * 32 + 9 + k];
        float mm = omb[p * 32 + 18 + k];
        mm = 1.f / (1.f + expf(-mm));
        float py = o1 + (float)(h + k / 3 - 1);
        float px = o2 + (float)(wt * 16 + p + k % 3 - 1);
        float y0f = floorf(py), x0f = floorf(px);
        float wy = py - y0f, wx = px - x0f;
        int y0 = (int)y0f, x0 = (int)x0f;
        bool y0v = (y0 >= 0) && (y0 < H);
        bool y1v = (y0 + 1 >= 0) && (y0 + 1 < H);
        bool x0v = (x0 >= 0) && (x0 < W);
        bool x1v = (x0 + 1 >= 0) && (x0 + 1 < W);
        int y0c = min(max(y0, 0), H - 1) * W;
        int y1c = min(max(y0 + 1, 0), H - 1) * W;
        int x0c = min(max(x0, 0), W - 1);
        int x1c = min(max(x0 + 1, 0), W - 1);
        int4 pi;
        pi.x = (y0c + x0c) * C; pi.y = (y0c + x1c) * C;
        pi.z = (y1c + x0c) * C; pi.w = (y1c + x1c) * C;
        float4 pw;
        pw.x = (y0v && x0v) ? (1.f - wy) * (1.f - wx) * mm : 0.f;
        pw.y = (y0v && x1v) ? (1.f - wy) * wx * mm : 0.f;
        pw.z = (y1v && x0v) ? wy * (1.f - wx) * mm : 0.f;
        pw.w = (y1v && x1v) ? wy * wx * mm : 0.f;
        pki[idx] = pi;
        pkw[idx] = pw;
    }
    __syncthreads();

    f32x4 acc[8];
#pragma unroll
    for (int i = 0; i < 8; i++) acc[i] = {0.f, 0.f, 0.f, 0.f};

    const __bf16* xb = xcl + (size_t)b * H * W * C;
    __bf16* sb = sbuf + wave * 1280;
    __bf16* wp0 = sb + pos16 * 40 + cq * 8;
    const __bf16* rp0 = sb + row * 40 + kg * 8;

    uint4 u00, u01, u10, u11;
    float4 pwc;
    bf16x8 Ba[8], Bb[8];

    auto LOADG = [&](int ls) {
        int k = ls / CHW, chl = ls - k * CHW;
        int4 pi = pki[k * 16 + pos16];
        pwc = pkw[k * 16 + pos16];
        int cb = (wave * CHW + chl) * 32 + cq * 8;
        u00 = *reinterpret_cast<const uint4*>(xb + pi.x + cb);
        u01 = *reinterpret_cast<const uint4*>(xb + pi.y + cb);
        u10 = *reinterpret_cast<const uint4*>(xb + pi.z + cb);
        u11 = *reinterpret_cast<const uint4*>(xb + pi.w + cb);
    };
    auto LOADBA = [&](int ls) {
        int k = ls / CHW, chl = ls - k * CHW;
        int sg = k * NCH + wave * CHW + chl;
        const __bf16* wbc = wkp + (size_t)sg * 4096 + lane * 8;
#pragma unroll
        for (int ot = 0; ot < 8; ot++)
            Ba[ot] = *reinterpret_cast<const bf16x8*>(wbc + ot * 512);
    };
    auto LOADBB = [&](int ls) {
        int k = ls / CHW, chl = ls - k * CHW;
        int sg = k * NCH + wave * CHW + chl;
        const __bf16* wbc = wkp + (size_t)sg * 4096 + lane * 8;
#pragma unroll
        for (int ot = 0; ot < 8; ot++)
            Bb[ot] = *reinterpret_cast<const bf16x8*>(wbc + ot * 512);
    };
    auto BLEND = [&](int bufoff) {
        bf16x8 v00 = __builtin_bit_cast(bf16x8, u00);
        bf16x8 v01 = __builtin_bit_cast(bf16x8, u01);
        bf16x8 v10 = __builtin_bit_cast(bf16x8, u10);
        bf16x8 v11 = __builtin_bit_cast(bf16x8, u11);
        bf16x8 rg;
#pragma unroll
        for (int j = 0; j < 8; j++) {
            float sv = pwc.x * (float)v00[j] + pwc.y * (float)v01[j]
                     + pwc.z * (float)v10[j] + pwc.w * (float)v11[j];
            rg[j] = (__bf16)sv;
        }
        *reinterpret_cast<bf16x8*>(wp0 + bufoff) = rg;
    };
    auto MFMAA = [&](int bufoff) {
        bf16x8 a = *reinterpret_cast<const bf16x8*>(rp0 + bufoff);
#pragma unroll
        for (int ot = 0; ot < 8; ot++)
            acc[ot] = __builtin_amdgcn_mfma_f32_16x16x32_bf16(a, Ba[ot], acc[ot], 0, 0, 0);
    };
    auto MFMAB = [&](int bufoff) {
        bf16x8 a = *reinterpret_cast<const bf16x8*>(rp0 + bufoff);
#pragma unroll
        for (int ot = 0; ot < 8; ot++)
            acc[ot] = __builtin_amdgcn_mfma_f32_16x16x32_bf16(a, Bb[ot], acc[ot], 0, 0, 0);
    };

    LOADBA(0);
    LOADG(0);
    for (int s = 0; s < NSW; s += 2) {
        BLEND(0);
        LOADBB(s + 1);
        LOADG(s + 1);
        MFMAA(0);
        BLEND(640);
        if (s + 2 < NSW) { LOADBA(s + 2); LOADG(s + 2); }
        MFMAB(640);
    }

    __syncthreads();
    if (wave > 0) {
        float* rd = reinterpret_cast<float*>(smem) + (wave - 1) * 2304;
#pragma unroll
        for (int ot = 0; ot < 8; ot++)
            *reinterpret_cast<f32x4*>(rd + lane * 36 + ot * 4) = acc[ot];
    }
    __syncthreads();
    if (wave == 0) {
        for (int s = 0; s < KS - 1; s++) {
            float* rd = reinterpret_cast<float*>(smem) + s * 2304;
#pragma unroll
            for (int ot = 0; ot < 8; ot++) {
                f32x4 v = *reinterpret_cast<const f32x4*>(rd + lane * 36 + ot * 4);
                acc[ot] += v;
            }
        }
        if (CF_OUT) {
            float* ob = outcf + (size_t)b * OO * H * W + (size_t)h * W + wt * 16;
#pragma unroll
            for (int ot = 0; ot < 8; ot++) {
                int o = ot * 16 + row;
                float s = sc[o], hh = sh[o];
#pragma unroll
                for (int j = 0; j < 4; j++) {
                    float y = fmaxf(acc[ot][j] * s + hh, 0.f);
                    ob[(size_t)o * H * W + kg * 4 + j] = y;
                }
            }
        } else {
            __bf16* ob = outcl + (((size_t)b * H + h) * W + wt * 16) * OO;
#pragma unroll
            for (int ot = 0; ot < 8; ot++) {
                int o = ot * 16 + row;
                float s = sc[o], hh = sh[o];
#pragma unroll
                for (int j = 0; j < 4; j++) {
                    float y = fmaxf(acc[ot][j] * s + hh, 0.f);
                    ob[(size_t)(kg * 4 + j) * OO + o] = (__bf16)y;
                }
            }
        }
    }
}

// ---------- DCN v10 (stage C): 4 wave-tiles + SHARED LDS B double-buffer ----------
// Cuts per-wave L1 line requests 192 -> 96: B-frags staged once per block (each wave
// copies its coalesced 2KB quarter), read back via conflict-free linear ds_read_b128.
// One barrier/step at TOP: its implicit vmcnt(0) drains gathers issued ~a full step
// earlier, so BLEND's wait is free. sbuf/pk/gather/epilogue identical to v9.
template<int C, int H, int W, bool CF_OUT>
__global__ __launch_bounds__(256) void dcn_mfma10_kernel(
    const __bf16* __restrict__ xcl,  // [B][H][W][C]
    const float* __restrict__ omcl,  // [B][H][W][32]
    const __bf16* __restrict__ wkp,  // [9][C/32][8][64][8] bf16 (pack_w)
    const float* __restrict__ sc, const float* __restrict__ sh,
    float* __restrict__ outcf,       // CF_OUT: [B][O][H][W] fp32
    __bf16* __restrict__ outcl)      // else:   [B][H][W][O] bf16
{
    constexpr int NCH = C / 32;
    constexpr int NSW = 9 * NCH;     // 36 for C=128

    int t = threadIdx.x;
    int wave = t >> 6, lane = t & 63;
    int row = lane & 15, kg = lane >> 4;
    int pos16 = lane >> 2, cq = lane & 3;

    __shared__ __align__(16) char smem[4 * 7168 + 16384];  // per-wave ws + B dbuf
    char* ws = smem + wave * 7168;
    int4*   pki  = reinterpret_cast<int4*>(ws);           // [144]
    float4* pkw  = reinterpret_cast<float4*>(ws + 2304);  // [144]
    __bf16* sb   = reinterpret_cast<__bf16*>(ws + 4608);  // [2][640]
    __bf16* Bbuf = reinterpret_cast<__bf16*>(smem + 28672); // [2][4096]

    const int nwt = W / 16;
    int tile = blockIdx.x * 4 + wave;
    int wt = tile % nwt;
    int h  = (tile / nwt) % H;
    int b  = tile / (nwt * H);

    // per-wave precompute (in-wave DS ordering; barrier(0) below also covers it)
    const float* omb = omcl + (((size_t)b * H + h) * W + wt * 16) * 32;
    for (int idx = lane; idx < 144; idx += 64) {
        int p = idx & 15;
        int k = idx >> 4;
        float o1 = omb[p * 32 + k];
        float o2 = omb[p * 32 + 9 + k];
        float mm = omb[p * 32 + 18 + k];
        mm = 1.f / (1.f + expf(-mm));
        float py = o1 + (float)(h + k / 3 - 1);
        float px = o2 + (float)(wt * 16 + p + k % 3 - 1);
        float y0f = floorf(py), x0f = floorf(px);
        float wy = py - y0f, wx = px - x0f;
        int y0 = (int)y0f, x0 = (int)x0f;
        bool y0v = (y0 >= 0) && (y0 < H);
        bool y1v = (y0 + 1 >= 0) && (y0 + 1 < H);
        bool x0v = (x0 >= 0) && (x0 < W);
        bool x1v = (x0 + 1 >= 0) && (x0 + 1 < W);
        int y0c = min(max(y0, 0), H - 1) * W;
        int y1c = min(max(y0 + 1, 0), H - 1) * W;
        int x0c = min(max(x0, 0), W - 1);
        int x1c = min(max(x0 + 1, 0), W - 1);
        int4 pi;
        pi.x = (y0c + x0c) * C; pi.y = (y0c + x1c) * C;
        pi.z = (y1c + x0c) * C; pi.w = (y1c + x1c) * C;
        float4 pw;
        pw.x = (y0v && x0v) ? (1.f - wy) * (1.f - wx) * mm : 0.f;
        pw.y = (y0v && x1v) ? (1.f - wy) * wx * mm : 0.f;
        pw.z = (y1v && x0v) ? wy * (1.f - wx) * mm : 0.f;
        pw.w = (y1v && x1v) ? wy * wx * mm : 0.f;
        pki[idx] = pi;
        pkw[idx] = pw;
    }

    f32x4 acc[8];
#pragma unroll
    for (int i = 0; i < 8; i++) acc[i] = {0.f, 0.f, 0.f, 0.f};

    const __bf16* xb = xcl + (size_t)b * H * W * C;
    __bf16* wp0 = sb + pos16 * 40 + cq * 8;
    const __bf16* rp0 = sb + row * 40 + kg * 8;

    uint4 u00, u01, u10, u11;
    float4 pwc;

    auto LOADG = [&](int ls) {
        int k = ls / NCH, chl = ls - k * NCH;
        int4 pi = pki[k * 16 + pos16];
        pwc = pkw[k * 16 + pos16];
        int cb = chl * 32 + cq * 8;
        u00 = *reinterpret_cast<const uint4*>(xb + pi.x + cb);
        u01 = *reinterpret_cast<const uint4*>(xb + pi.y + cb);
        u10 = *reinterpret_cast<const uint4*>(xb + pi.z + cb);
        u11 = *reinterpret_cast<const uint4*>(xb + pi.w + cb);
    };
    auto BLEND = [&](int bufoff) {
        bf16x8 v00 = __builtin_bit_cast(bf16x8, u00);
        bf16x8 v01 = __builtin_bit_cast(bf16x8, u01);
        bf16x8 v10 = __builtin_bit_cast(bf16x8, u10);
        bf16x8 v11 = __builtin_bit_cast(bf16x8, u11);
        bf16x8 rg;
#pragma unroll
        for (int j = 0; j < 8; j++) {
            float sv = pwc.x * (float)v00[j] + pwc.y * (float)v01[j]
                     + pwc.z * (float)v10[j] + pwc.w * (float)v11[j];
            rg[j] = (__bf16)sv;
        }
        *reinterpret_cast<bf16x8*>(wp0 + bufoff) = rg;
    };

    // prologue: stage B(0) into Bbuf[0] (each wave its coalesced 2KB quarter); gathers(0)
    {
        const __bf16* src = wkp + (size_t)0 * 4096 + wave * 1024 + lane * 8;
        uint4 sv0 = *reinterpret_cast<const uint4*>(src);
        uint4 sv1 = *reinterpret_cast<const uint4*>(src + 512);
        LOADG(0);
        __bf16* dst = Bbuf + wave * 1024;
        *reinterpret_cast<uint4*>(dst + lane * 8) = sv0;
        *reinterpret_cast<uint4*>(dst + 512 + lane * 8) = sv1;
    }

    for (int s = 0; s < NSW; s++) {
        __syncthreads();   // buf[s&1] staged; drains gathers(s) (issued ~a step ago)
        int bsel = (s & 1) * 4096;
        bf16x8 Breg[8];
#pragma unroll
        for (int ot = 0; ot < 8; ot++)
            Breg[ot] = *reinterpret_cast<const bf16x8*>(Bbuf + bsel + ot * 512 + lane * 8);
        bool st = (s + 1 < NSW);
        uint4 sv0, sv1;
        if (st) {   // issue next-B stage loads (coalesced; 32 lines/wave)
            const __bf16* src = wkp + (size_t)(s + 1) * 4096 + wave * 1024 + lane * 8;
            sv0 = *reinterpret_cast<const uint4*>(src);
            sv1 = *reinterpret_cast<const uint4*>(src + 512);
        }
        BLEND((s & 1) * 640);             // gathers(s) already drained -> free
        if (st) LOADG(s + 1);             // drained at barrier(s+1) after ~full step
        bf16x8 a = *reinterpret_cast<const bf16x8*>(rp0 + (s & 1) * 640);
#pragma unroll
        for (int ot = 0; ot < 8; ot++)
            acc[ot] = __builtin_amdgcn_mfma_f32_16x16x32_bf16(a, Breg[ot], acc[ot], 0, 0, 0);
        if (st) {   // write staged B into buf[(s+1)&1]
            __bf16* dst = Bbuf + ((s + 1) & 1) * 4096 + wave * 1024;
            *reinterpret_cast<uint4*>(dst + lane * 8) = sv0;
            *reinterpret_cast<uint4*>(dst + 512 + lane * 8) = sv1;
        }
    }

    // epilogue (every wave its own tile), D map: o = ot*16+row, pos = kg*4+j
    if (CF_OUT) {
        float* ob = outcf + (size_t)b * OO * H * W + (size_t)h * W + wt * 16;
#pragma unroll
        for (int ot = 0; ot < 8; ot++) {
            int o = ot * 16 + row;
            float s = sc[o], hh = sh[o];
#pragma unroll
            for (int j = 0; j < 4; j++) {
                float y = fmaxf(acc[ot][j] * s + hh, 0.f);
                ob[(size_t)o * H * W + kg * 4 + j] = y;
            }
        }
    } else {
        __bf16* ob = outcl + (((size_t)b * H + h) * W + wt * 16) * OO;
#pragma unroll
        for (int ot = 0; ot < 8; ot++) {
            int o = ot * 16 + row;
            float s = sc[o], hh = sh[o];
#pragma unroll
            for (int j = 0; j < 4; j++) {
                float y = fmaxf(acc[ot][j] * s + hh, 0.f);
                ob[(size_t)(kg * 4 + j) * OO + o] = (__bf16)y;
            }
        }
    }
}

// ---------- bilinear x2 depthwise transposed conv + residual ----------
__global__ __launch_bounds__(256) void upsample_cl_kernel(
    const __bf16* __restrict__ h1cl,  // [B][HA][WA][O] bf16
    const float* __restrict__ prex,   // [B][O][HC][WC] fp32
    const float* __restrict__ upwt,   // [16][O]
    __bf16* __restrict__ zcl)         // [B][HC][WC][O] bf16
{
    int idx = blockIdx.x * blockDim.x + threadIdx.x;
    int x  = idx & (WC - 1);
    int y  = (idx >> 8) & (HC - 1);
    int cg = (idx >> 15) & 15;
    int b  = idx >> 19;

    int sy0, iy0, sy1, iy1, sx0, ix0, sx1, ix1;
    if (y & 1) { sy0 = (y - 1) >> 1; iy0 = 2; sy1 = sy0 + 1; iy1 = 0; }
    else       { sy0 = (y >> 1) - 1; iy0 = 3; sy1 = sy0 + 1; iy1 = 1; }
    if (x & 1) { sx0 = (x - 1) >> 1; ix0 = 2; sx1 = sx0 + 1; ix1 = 0; }
    else       { sx0 = (x >> 1) - 1; ix0 = 3; sx1 = sx0 + 1; ix1 = 1; }

    int c0 = cg * 8;
    float acc[8];
    const float* pp = prex + ((size_t)b * OO + c0) * (HC * WC) + (size_t)y * WC + x;
#pragma unroll
    for (int j = 0; j < 8; j++) acc[j] = pp[(size_t)j * HC * WC];

    bool y0v = sy0 >= 0, y1v = sy1 < HA;
    bool x0v = sx0 >= 0, x1v = sx1 < WA;
    const __bf16* hb = h1cl + (size_t)b * HA * WA * OO + c0;

    auto tap = [&](int sy, int sx, int wi) {
        uint4 u = *reinterpret_cast<const uint4*>(hb + ((size_t)sy * WA + sx) * OO);
        bf16x8 v = __builtin_bit_cast(bf16x8, u);
        const float* wp = upwt + wi * OO + c0;
#pragma unroll
        for (int j = 0; j < 8; j++) acc[j] += (float)v[j] * wp[j];
    };
    if (y0v && x0v) tap(sy0, sx0, iy0 * 4 + ix0);
    if (y0v && x1v) tap(sy0, sx1, iy0 * 4 + ix1);
    if (y1v && x0v) tap(sy1, sx0, iy1 * 4 + ix0);
    if (y1v && x1v) tap(sy1, sx1, iy1 * 4 + ix1);

    bf16x8 r;
#pragma unroll
    for (int j = 0; j < 8; j++) r[j] = (__bf16)acc[j];
    *reinterpret_cast<bf16x8*>(zcl + (((size_t)b * HC + y) * WC + x) * OO + c0) = r;
}

// ---------------- launch ----------------
extern "C" void kernel_launch(void* const* d_in, const int* in_sizes, int n_in,
                              void* d_out, int out_size, void* d_ws, size_t ws_size,
                              hipStream_t stream) {
    (void)in_sizes; (void)n_in; (void)out_size; (void)ws_size;
    const float* x      = (const float*)d_in[0];
    const float* pre_x  = (const float*)d_in[1];
    const float* pwom   = (const float*)d_in[2];
    const float* pbom   = (const float*)d_in[3];
    const float* pw     = (const float*)d_in[4];
    const float* pb     = (const float*)d_in[5];
    const float* pgam   = (const float*)d_in[6];
    const float* pbet   = (const float*)d_in[7];
    const float* pmea   = (const float*)d_in[8];
    const float* pvar   = (const float*)d_in[9];
    const float* nwom   = (const float*)d_in[10];
    const float* nbom   = (const float*)d_in[11];
    const float* nw     = (const float*)d_in[12];
    const float* nb     = (const float*)d_in[13];
    const float* ngam   = (const float*)d_in[14];
    const float* nbet   = (const float*)d_in[15];
    const float* nmea   = (const float*)d_in[16];
    const float* nvar   = (const float*)d_in[17];
    const float* upw    = (const float*)d_in[18];
    float* out = (float*)d_out;

    char* wsb = (char*)d_ws;
    __bf16* xclA  = (__bf16*)(wsb + 0);          //  8,388,608 B
    __bf16* h1cl  = (__bf16*)(wsb + 8388608);    //  4,194,304
    __bf16* zcl   = (__bf16*)(wsb + 12582912);   // 16,777,216
    float*  omA   = (float*) (wsb + 29360128);   //  2,097,152
    float*  omC   = (float*) (wsb + 31457280);   //  8,388,608
    __bf16* wkAp  = (__bf16*)(wsb + 39845888);   //    589,824
    __bf16* wkCp  = (__bf16*)(wsb + 40435712);   //    294,912
    __bf16* womAp = (__bf16*)(wsb + 40730624);   //    147,456
    __bf16* womCp = (__bf16*)(wsb + 40878080);   //     73,728
    float*  upwt  = (float*) (wsb + 40951808);   //      8,192
    float*  scA   = (float*) (wsb + 40960000);
    float*  shA   = (float*) (wsb + 40960512);
    float*  scC   = (float*) (wsb + 40961024);
    float*  shC   = (float*) (wsb + 40961536);   // end ~41.0 MB

    // prepacks
    pack_w_kernel<<<1152, 256, 0, stream>>>(pw, wkAp, CA, 8, 128);
    pack_w_kernel<<<576, 256, 0, stream>>>(nw, wkCp, CC, 8, 128);
    pack_w_kernel<<<288, 256, 0, stream>>>(pwom, womAp, CA, 2, 27);
    pack_w_kernel<<<144, 256, 0, stream>>>(nwom, womCp, CC, 2, 27);
    bn_prepack_kernel<<<1, 128, 0, stream>>>(pgam, pbet, pmea, pvar, pb, scA, shA);
    bn_prepack_kernel<<<1, 128, 0, stream>>>(ngam, nbet, nmea, nvar, nb, scC, shC);
    pack_upw_kernel<<<8, 256, 0, stream>>>(upw, upwt);
    to_cl_kernel<CA, HA*WA><<<BN2 * (CA/32) * (HA*WA/64), 256, 0, stream>>>(x, xclA);

    // stage A
    om_mfma_kernel<CA, HA, WA><<<BN2 * HA * (WA/64), 256, 0, stream>>>(xclA, womAp, pbom, omA);
    dcn_mfma6_kernel<CA, HA, WA, 4, false><<<BN2 * HA * (WA/16), 256, 0, stream>>>(
        xclA, omA, wkAp, scA, shA, nullptr, h1cl);

    // upsample + residual
    upsample_cl_kernel<<<(BN2 * 16 * HC * WC) / 256, 256, 0, stream>>>(h1cl, pre_x, upwt, zcl);

    // stage C — v10: 4 wave-tiles sharing LDS-staged B fragments
    om_mfma_kernel<CC, HC, WC><<<BN2 * HC * (WC/64), 256, 0, stream>>>(zcl, womCp, nbom, omC);
    dcn_mfma10_kernel<CC, HC, WC, true><<<BN2 * HC * (WC/16) / 4, 256, 0, stream>>>(
        zcl, omC, wkCp, scC, shC, out, nullptr);
}

// Round 18
// 178.588 us; speedup vs baseline: 1.3395x; 1.0132x over previous
//
#include <hip/hip_runtime.h>
#include <hip/hip_bf16.h>
#include <math.h>

typedef __bf16 bf16x8 __attribute__((ext_vector_type(8)));
typedef float  f32x4  __attribute__((ext_vector_type(4)));

static constexpr int BN2 = 2;
static constexpr int CA = 256, HA = 64, WA = 128;   // stage A input
static constexpr int OO = 128;                      // output channels
static constexpr int HC = 128, WC = 256, CC = 128;  // stage C

// ---------- pack weights into MFMA B-fragment layout: [9][C/32][OT][64][8] bf16 ----------
__global__ void pack_w_kernel(const float* __restrict__ w, __bf16* __restrict__ out,
                              int Cin, int OT, int Oreal) {
    int NCH = Cin / 32;
    int idx = blockIdx.x * blockDim.x + threadIdx.x;
    int total = 9 * NCH * OT * 512;
    if (idx >= total) return;
    int j    = idx & 7;
    int lane = (idx >> 3) & 63;
    int ot   = (idx >> 9) % OT;
    int rest = (idx >> 9) / OT;
    int ch = rest % NCH;
    int k  = rest / NCH;
    int o = ot * 16 + (lane & 15);
    int c = ch * 32 + (lane >> 4) * 8 + j;
    float v = (o < Oreal) ? w[((size_t)o * Cin + c) * 9 + k] : 0.f;
    out[idx] = (__bf16)v;
}

// ---------- NCHW fp32 -> NHWC bf16 (LDS tile transpose) ----------
template<int C, int HW>
__global__ __launch_bounds__(256) void to_cl_kernel(const float* __restrict__ x,
                                                    __bf16* __restrict__ xcl) {
    constexpr int NCB = C / 32;
    constexpr int NPB = HW / 64;
    int blk = blockIdx.x;
    int pblk = blk % NPB;
    int cblk = (blk / NPB) % NCB;
    int b = blk / (NPB * NCB);
    int t = threadIdx.x;
    __shared__ float st[32][65];
    int r = t >> 6, q = t & 63;
#pragma unroll
    for (int i = 0; i < 8; i++) {
        int c = cblk * 32 + i * 4 + r;
        st[i * 4 + r][q] = x[((size_t)b * C + c) * HW + pblk * 64 + q];
    }
    __syncthreads();
    int p = t >> 2, cq = t & 3;
    bf16x8 v;
#pragma unroll
    for (int j = 0; j < 8; j++) v[j] = (__bf16)st[cq * 8 + j][p];
    *reinterpret_cast<bf16x8*>(xcl + ((size_t)b * HW + pblk * 64 + p) * C + cblk * 32 + cq * 8) = v;
}

// ---------- fold bias+BN into per-o scale/shift ----------
__global__ void bn_prepack_kernel(const float* __restrict__ g,  const float* __restrict__ be,
                                  const float* __restrict__ mu, const float* __restrict__ va,
                                  const float* __restrict__ bi,
                                  float* __restrict__ sc, float* __restrict__ sh) {
    int i = blockIdx.x * blockDim.x + threadIdx.x;
    if (i >= OO) return;
    float s = g[i] * rsqrtf(va[i] + 1e-5f);
    sc[i] = s;
    sh[i] = (bi[i] - mu[i]) * s + be[i];
}

// ---------- upw[O][4][4] -> upwt[16][O] ----------
__global__ void pack_upw_kernel(const float* __restrict__ upw, float* __restrict__ upwt) {
    int idx = blockIdx.x * blockDim.x + threadIdx.x;
    if (idx >= 16 * OO) return;
    int i = idx >> 7;
    int o = idx & 127;
    upwt[i * OO + o] = upw[o * 16 + i];
}

// ---------- om-conv as MFMA, PIXEL-MAJOR window: b128 staging + b128 A-frag reads ----------
// win[pix][RS=36] bf16 (pad 4): write = 1 ds_write_b128/lane (linear), A-frag =
// 1 ds_read_b128 (8 contiguous channels). RS=18 dwords; 16 rows of a kg-group hit
// 16 distinct bank offsets (gcd(18,32)=2, cycle 16) -> conflict-free.
template<int C, int H, int W>
__global__ __launch_bounds__(256) void om_mfma_kernel(
    const __bf16* __restrict__ xcl,   // [B][H][W][C]
    const __bf16* __restrict__ womp,  // [9][C/32][2][64][8] bf16
    const float* __restrict__ bom,    // [27]
    float* __restrict__ omcl)         // [B][H][W][32]
{
    constexpr int NCH = C / 32;
    constexpr int RS = 36;
    const int nwt = W / 64;
    int wt = blockIdx.x % nwt;
    int h  = (blockIdx.x / nwt) % H;
    int b  = blockIdx.x / (nwt * H);
    int t = threadIdx.x;
    int wave = t >> 6, lane = t & 63;
    int row = lane & 15, kg = lane >> 4;

    __shared__ __bf16 win[198 * RS];   // 14256 B

    f32x4 acc0 = {0.f, 0.f, 0.f, 0.f};
    f32x4 acc1 = {0.f, 0.f, 0.f, 0.f};
    const __bf16* xb = xcl + (size_t)b * H * W * C;

    for (int ch = 0; ch < NCH; ch++) {
        for (int i = 0; i < 4; i++) {
            int idx = i * 256 + t;
            if (idx < 792) {
                int cq  = idx & 3;
                int pix = idx >> 2;           // 0..197 = ry*66+rx
                int ry = pix / 66, rx = pix % 66;
                int y = h + ry - 1, xx = wt * 64 + rx - 1;
                bool valid = (y >= 0) && (y < H) && (xx >= 0) && (xx < W);
                int yc = min(max(y, 0), H - 1), xc = min(max(xx, 0), W - 1);
                uint4 u = *reinterpret_cast<const uint4*>(
                    xb + ((size_t)yc * W + xc) * C + ch * 32 + cq * 8);
                if (!valid) { u.x = 0; u.y = 0; u.z = 0; u.w = 0; }
                *reinterpret_cast<uint4*>(&win[pix * RS + cq * 8]) = u;
            }
        }
        __syncthreads();
#pragma unroll
        for (int k = 0; k < 9; k++) {
            int off = (k / 3) * 66 + (k % 3) + wave * 16 + row;
            bf16x8 a = *reinterpret_cast<const bf16x8*>(&win[off * RS + kg * 8]);
            const __bf16* wbc = womp + ((size_t)k * NCH + ch) * 1024 + lane * 8;
            bf16x8 b0 = *reinterpret_cast<const bf16x8*>(wbc);
            bf16x8 b1 = *reinterpret_cast<const bf16x8*>(wbc + 512);
            acc0 = __builtin_amdgcn_mfma_f32_16x16x32_bf16(a, b0, acc0, 0, 0, 0);
            acc1 = __builtin_amdgcn_mfma_f32_16x16x32_bf16(a, b1, acc1, 0, 0, 0);
        }
        __syncthreads();
    }

    float* ob = omcl + (((size_t)b * H + h) * W + wt * 64 + wave * 16 + kg * 4) * 32;
    float bb0 = bom[row];
#pragma unroll
    for (int j = 0; j < 4; j++)
        ob[(size_t)j * 32 + row] = acc0[j] + bb0;
    if (row < 11) {
        float bb1 = bom[16 + row];
#pragma unroll
        for (int j = 0; j < 4; j++)
            ob[(size_t)j * 32 + 16 + row] = acc1[j] + bb1;
    }
}

// ---------- DCN v6 (r11/r13/r14-proven): 16-pos tiles + split-K + B-prefetch ----------
template<int C, int H, int W, int KS, bool CF_OUT>
__global__ __launch_bounds__(64 * KS) void dcn_mfma6_kernel(
    const __bf16* __restrict__ xcl,  // [B][H][W][C]
    const float* __restrict__ omcl,  // [B][H][W][32]
    const __bf16* __restrict__ wkp,  // [9][C/32][8][64][8] bf16 (pack_w)
    const float* __restrict__ sc, const float* __restrict__ sh,
    float* __restrict__ outcf,       // CF_OUT: [B][O][H][W] fp32
    __bf16* __restrict__ outcl)      // else:   [B][H][W][O] bf16
{
    constexpr int NCH = C / 32;
    constexpr int CHW = NCH / KS;
    constexpr int NSW = 9 * CHW;
    static_assert(NSW % 2 == 0, "unroll-by-2 needs even NSW");
    constexpr int MAIN = 4608 + KS * 2560;
    constexpr int RED  = (KS - 1) * 9216;
    constexpr int SMEM = MAIN > RED ? MAIN : RED;

    const int nwt = W / 16;
    int wt = blockIdx.x % nwt;
    int h  = (blockIdx.x / nwt) % H;
    int b  = blockIdx.x / (nwt * H);
    int t = threadIdx.x;
    int wave = t >> 6, lane = t & 63;
    int row = lane & 15, kg = lane >> 4;
    int pos16 = lane >> 2, cq = lane & 3;

    __shared__ __align__(16) char smem[SMEM];
    int4*   pki  = reinterpret_cast<int4*>(smem);            // [144]
    float4* pkw  = reinterpret_cast<float4*>(smem + 2304);   // [144]
    __bf16* sbuf = reinterpret_cast<__bf16*>(smem + 4608);   // [KS][2][16*40]

    const float* omb = omcl + (((size_t)b * H + h) * W + wt * 16) * 32;
    for (int idx = t; idx < 144; idx += 64 * KS) {
        int p = idx & 15;
        int k = idx >> 4;
        float o1 = omb[p * 32 + k];
        float o2 = omb[p * 32 + 9 + k];
        float mm = omb[p * 32 + 18 + k];
        mm = 1.f / (1.f + expf(-mm));
        float py = o1 + (float)(h + k / 3 - 1);
        float px = o2 + (float)(wt * 16 + p + k % 3 - 1);
        float y0f = floorf(py), x0f = floorf(px);
        float wy = py - y0f, wx = px - x0f;
        int y0 = (int)y0f, x0 = (int)x0f;
        bool y0v = (y0 >= 0) && (y0 < H);
        bool y1v = (y0 + 1 >= 0) && (y0 + 1 < H);
        bool x0v = (x0 >= 0) && (x0 < W);
        bool x1v = (x0 + 1 >= 0) && (x0 + 1 < W);
        int y0c = min(max(y0, 0), H - 1) * W;
        int y1c = min(max(y0 + 1, 0), H - 1) * W;
        int x0c = min(max(x0, 0), W - 1);
        int x1c = min(max(x0 + 1, 0), W - 1);
        int4 pi;
        pi.x = (y0c + x0c) * C; pi.y = (y0c + x1c) * C;
        pi.z = (y1c + x0c) * C; pi.w = (y1c + x1c) * C;
        float4 pw;
        pw.x = (y0v && x0v) ? (1.f - wy) * (1.f - wx) * mm : 0.f;
        pw.y = (y0v && x1v) ? (1.f - wy) * wx * mm : 0.f;
        pw.z = (y1v && x0v) ? wy * (1.f - wx) * mm : 0.f;
        pw.w = (y1v && x1v) ? wy * wx * mm : 0.f;
        pki[idx] = pi;
        pkw[idx] = pw;
    }
    __syncthreads();

    f32x4 acc[8];
#pragma unroll
    for (int i = 0; i < 8; i++) acc[i] = {0.f, 0.f, 0.f, 0.f};

    const __bf16* xb = xcl + (size_t)b * H * W * C;
    __bf16* sb = sbuf + wave * 1280;
    __bf16* wp0 = sb + pos16 * 40 + cq * 8;
    const __bf16* rp0 = sb + row * 40 + kg * 8;

    uint4 u00, u01, u10, u11;
    float4 pwc;
    bf16x8 Ba[8], Bb[8];

    auto LOADG = [&](int ls) {
        int k = ls / CHW, chl = ls - k * CHW;
        int4 pi = pki[k * 16 + pos16];
        pwc = pkw[k * 16 + pos16];
        int cb = (wave * CHW + chl) * 32 + cq * 8;
        u00 = *reinterpret_cast<const uint4*>(xb + pi.x + cb);
        u01 = *reinterpret_cast<const uint4*>(xb + pi.y + cb);
        u10 = *reinterpret_cast<const uint4*>(xb + pi.z + cb);
        u11 = *reinterpret_cast<const uint4*>(xb + pi.w + cb);
    };
    auto LOADBA = [&](int ls) {
        int k = ls / CHW, chl = ls - k * CHW;
        int sg = k * NCH + wave * CHW + chl;
        const __bf16* wbc = wkp + (size_t)sg * 4096 + lane * 8;
#pragma unroll
        for (int ot = 0; ot < 8; ot++)
            Ba[ot] = *reinterpret_cast<const bf16x8*>(wbc + ot * 512);
    };
    auto LOADBB = [&](int ls) {
        int k = ls / CHW, chl = ls - k * CHW;
        int sg = k * NCH + wave * CHW + chl;
        const __bf16* wbc = wkp + (size_t)sg * 4096 + lane * 8;
#pragma unroll
        for (int ot = 0; ot < 8; ot++)
            Bb[ot] = *reinterpret_cast<const bf16x8*>(wbc + ot * 512);
    };
    auto BLEND = [&](int bufoff) {
        bf16x8 v00 = __builtin_bit_cast(bf16x8, u00);
        bf16x8 v01 = __builtin_bit_cast(bf16x8, u01);
        bf16x8 v10 = __builtin_bit_cast(bf16x8, u10);
        bf16x8 v11 = __builtin_bit_cast(bf16x8, u11);
        bf16x8 rg;
#pragma unroll
        for (int j = 0; j < 8; j++) {
            float sv = pwc.x * (float)v00[j] + pwc.y * (float)v01[j]
                     + pwc.z * (float)v10[j] + pwc.w * (float)v11[j];
            rg[j] = (__bf16)sv;
        }
        *reinterpret_cast<bf16x8*>(wp0 + bufoff) = rg;
    };
    auto MFMAA = [&](int bufoff) {
        bf16x8 a = *reinterpret_cast<const bf16x8*>(rp0 + bufoff);
#pragma unroll
        for (int ot = 0; ot < 8; ot++)
            acc[ot] = __builtin_amdgcn_mfma_f32_16x16x32_bf16(a, Ba[ot], acc[ot], 0, 0, 0);
    };
    auto MFMAB = [&](int bufoff) {
        bf16x8 a = *reinterpret_cast<const bf16x8*>(rp0 + bufoff);
#pragma unroll
        for (int ot = 0; ot < 8; ot++)
            acc[ot] = __builtin_amdgcn_mfma_f32_16x16x32_bf16(a, Bb[ot], acc[ot], 0, 0, 0);
    };

    LOADBA(0);
    LOADG(0);
    for (int s = 0; s < NSW; s += 2) {
        BLEND(0);
        LOADBB(s + 1);
        LOADG(s + 1);
        MFMAA(0);
        BLEND(640);
        if (s + 2 < NSW) { LOADBA(s + 2); LOADG(s + 2); }
        MFMAB(640);
    }

    __syncthreads();
    if (wave > 0) {
        float* rd = reinterpret_cast<float*>(smem) + (wave - 1) * 2304;
#pragma unroll
        for (int ot = 0; ot < 8; ot++)
            *reinterpret_cast<f32x4*>(rd + lane * 36 + ot * 4) = acc[ot];
    }
    __syncthreads();
    if (wave == 0) {
        for (int s = 0; s < KS - 1; s++) {
            float* rd = reinterpret_cast<float*>(smem) + s * 2304;
#pragma unroll
            for (int ot = 0; ot < 8; ot++) {
                f32x4 v = *reinterpret_cast<const f32x4*>(rd + lane * 36 + ot * 4);
                acc[ot] += v;
            }
        }
        if (CF_OUT) {
            float* ob = outcf + (size_t)b * OO * H * W + (size_t)h * W + wt * 16;
#pragma unroll
            for (int ot = 0; ot < 8; ot++) {
                int o = ot * 16 + row;
                float s = sc[o], hh = sh[o];
#pragma unroll
                for (int j = 0; j < 4; j++) {
                    float y = fmaxf(acc[ot][j] * s + hh, 0.f);
                    ob[(size_t)o * H * W + kg * 4 + j] = y;
                }
            }
        } else {
            __bf16* ob = outcl + (((size_t)b * H + h) * W + wt * 16) * OO;
#pragma unroll
            for (int ot = 0; ot < 8; ot++) {
                int o = ot * 16 + row;
                float s = sc[o], hh = sh[o];
#pragma unroll
                for (int j = 0; j < 4; j++) {
                    float y = fmaxf(acc[ot][j] * s + hh, 0.f);
                    ob[(size_t)(kg * 4 + j) * OO + o] = (__bf16)y;
                }
            }
        }
    }
}

// ---------- DCN v10 (stage C): 4 wave-tiles + SHARED LDS B double-buffer (r17-proven) ----------
template<int C, int H, int W, bool CF_OUT>
__global__ __launch_bounds__(256) void dcn_mfma10_kernel(
    const __bf16* __restrict__ xcl,  // [B][H][W][C]
    const float* __restrict__ omcl,  // [B][H][W][32]
    const __bf16* __restrict__ wkp,  // [9][C/32][8][64][8] bf16 (pack_w)
    const float* __restrict__ sc, const float* __restrict__ sh,
    float* __restrict__ outcf,       // CF_OUT: [B][O][H][W] fp32
    __bf16* __restrict__ outcl)      // else:   [B][H][W][O] bf16
{
    constexpr int NCH = C / 32;
    constexpr int NSW = 9 * NCH;     // 36 for C=128

    int t = threadIdx.x;
    int wave = t >> 6, lane = t & 63;
    int row = lane & 15, kg = lane >> 4;
    int pos16 = lane >> 2, cq = lane & 3;

    __shared__ __align__(16) char smem[4 * 7168 + 16384];  // per-wave ws + B dbuf
    char* ws = smem + wave * 7168;
    int4*   pki  = reinterpret_cast<int4*>(ws);           // [144]
    float4* pkw  = reinterpret_cast<float4*>(ws + 2304);  // [144]
    __bf16* sb   = reinterpret_cast<__bf16*>(ws + 4608);  // [2][640]
    __bf16* Bbuf = reinterpret_cast<__bf16*>(smem + 28672); // [2][4096]

    const int nwt = W / 16;
    int tile = blockIdx.x * 4 + wave;
    int wt = tile % nwt;
    int h  = (tile / nwt) % H;
    int b  = tile / (nwt * H);

    const float* omb = omcl + (((size_t)b * H + h) * W + wt * 16) * 32;
    for (int idx = lane; idx < 144; idx += 64) {
        int p = idx & 15;
        int k = idx >> 4;
        float o1 = omb[p * 32 + k];
        float o2 = omb[p * 32 + 9 + k];
        float mm = omb[p * 32 + 18 + k];
        mm = 1.f / (1.f + expf(-mm));
        float py = o1 + (float)(h + k / 3 - 1);
        float px = o2 + (float)(wt * 16 + p + k % 3 - 1);
        float y0f = floorf(py), x0f = floorf(px);
        float wy = py - y0f, wx = px - x0f;
        int y0 = (int)y0f, x0 = (int)x0f;
        bool y0v = (y0 >= 0) && (y0 < H);
        bool y1v = (y0 + 1 >= 0) && (y0 + 1 < H);
        bool x0v = (x0 >= 0) && (x0 < W);
        bool x1v = (x0 + 1 >= 0) && (x0 + 1 < W);
        int y0c = min(max(y0, 0), H - 1) * W;
        int y1c = min(max(y0 + 1, 0), H - 1) * W;
        int x0c = min(max(x0, 0), W - 1);
        int x1c = min(max(x0 + 1, 0), W - 1);
        int4 pi;
        pi.x = (y0c + x0c) * C; pi.y = (y0c + x1c) * C;
        pi.z = (y1c + x0c) * C; pi.w = (y1c + x1c) * C;
        float4 pw;
        pw.x = (y0v && x0v) ? (1.f - wy) * (1.f - wx) * mm : 0.f;
        pw.y = (y0v && x1v) ? (1.f - wy) * wx * mm : 0.f;
        pw.z = (y1v && x0v) ? wy * (1.f - wx) * mm : 0.f;
        pw.w = (y1v && x1v) ? wy * wx * mm : 0.f;
        pki[idx] = pi;
        pkw[idx] = pw;
    }

    f32x4 acc[8];
#pragma unroll
    for (int i = 0; i < 8; i++) acc[i] = {0.f, 0.f, 0.f, 0.f};

    const __bf16* xb = xcl + (size_t)b * H * W * C;
    __bf16* wp0 = sb + pos16 * 40 + cq * 8;
    const __bf16* rp0 = sb + row * 40 + kg * 8;

    uint4 u00, u01, u10, u11;
    float4 pwc;

    auto LOADG = [&](int ls) {
        int k = ls / NCH, chl = ls - k * NCH;
        int4 pi = pki[k * 16 + pos16];
        pwc = pkw[k * 16 + pos16];
        int cb = chl * 32 + cq * 8;
        u00 = *reinterpret_cast<const uint4*>(xb + pi.x + cb);
        u01 = *reinterpret_cast<const uint4*>(xb + pi.y + cb);
        u10 = *reinterpret_cast<const uint4*>(xb + pi.z + cb);
        u11 = *reinterpret_cast<const uint4*>(xb + pi.w + cb);
    };
    auto BLEND = [&](int bufoff) {
        bf16x8 v00 = __builtin_bit_cast(bf16x8, u00);
        bf16x8 v01 = __builtin_bit_cast(bf16x8, u01);
        bf16x8 v10 = __builtin_bit_cast(bf16x8, u10);
        bf16x8 v11 = __builtin_bit_cast(bf16x8, u11);
        bf16x8 rg;
#pragma unroll
        for (int j = 0; j < 8; j++) {
            float sv = pwc.x * (float)v00[j] + pwc.y * (float)v01[j]
                     + pwc.z * (float)v10[j] + pwc.w * (float)v11[j];
            rg[j] = (__bf16)sv;
        }
        *reinterpret_cast<bf16x8*>(wp0 + bufoff) = rg;
    };

    // prologue: stage B(0) into Bbuf[0]; gathers(0)
    {
        const __bf16* src = wkp + (size_t)0 * 4096 + wave * 1024 + lane * 8;
        uint4 sv0 = *reinterpret_cast<const uint4*>(src);
        uint4 sv1 = *reinterpret_cast<const uint4*>(src + 512);
        LOADG(0);
        __bf16* dst = Bbuf + wave * 1024;
        *reinterpret_cast<uint4*>(dst + lane * 8) = sv0;
        *reinterpret_cast<uint4*>(dst + 512 + lane * 8) = sv1;
    }

    for (int s = 0; s < NSW; s++) {
        __syncthreads();
        int bsel = (s & 1) * 4096;
        bf16x8 Breg[8];
#pragma unroll
        for (int ot = 0; ot < 8; ot++)
            Breg[ot] = *reinterpret_cast<const bf16x8*>(Bbuf + bsel + ot * 512 + lane * 8);
        bool st = (s + 1 < NSW);
        uint4 sv0, sv1;
        if (st) {
            const __bf16* src = wkp + (size_t)(s + 1) * 4096 + wave * 1024 + lane * 8;
            sv0 = *reinterpret_cast<const uint4*>(src);
            sv1 = *reinterpret_cast<const uint4*>(src + 512);
        }
        BLEND((s & 1) * 640);
        if (st) LOADG(s + 1);
        bf16x8 a = *reinterpret_cast<const bf16x8*>(rp0 + (s & 1) * 640);
#pragma unroll
        for (int ot = 0; ot < 8; ot++)
            acc[ot] = __builtin_amdgcn_mfma_f32_16x16x32_bf16(a, Breg[ot], acc[ot], 0, 0, 0);
        if (st) {
            __bf16* dst = Bbuf + ((s + 1) & 1) * 4096 + wave * 1024;
            *reinterpret_cast<uint4*>(dst + lane * 8) = sv0;
            *reinterpret_cast<uint4*>(dst + 512 + lane * 8) = sv1;
        }
    }

    if (CF_OUT) {
        float* ob = outcf + (size_t)b * OO * H * W + (size_t)h * W + wt * 16;
#pragma unroll
        for (int ot = 0; ot < 8; ot++) {
            int o = ot * 16 + row;
            float s = sc[o], hh = sh[o];
#pragma unroll
            for (int j = 0; j < 4; j++) {
                float y = fmaxf(acc[ot][j] * s + hh, 0.f);
                ob[(size_t)o * H * W + kg * 4 + j] = y;
            }
        }
    } else {
        __bf16* ob = outcl + (((size_t)b * H + h) * W + wt * 16) * OO;
#pragma unroll
        for (int ot = 0; ot < 8; ot++) {
            int o = ot * 16 + row;
            float s = sc[o], hh = sh[o];
#pragma unroll
            for (int j = 0; j < 4; j++) {
                float y = fmaxf(acc[ot][j] * s + hh, 0.f);
                ob[(size_t)(kg * 4 + j) * OO + o] = (__bf16)y;
            }
        }
    }
}

// ---------- bilinear x2 depthwise transposed conv + residual ----------
__global__ __launch_bounds__(256) void upsample_cl_kernel(
    const __bf16* __restrict__ h1cl,  // [B][HA][WA][O] bf16
    const float* __restrict__ prex,   // [B][O][HC][WC] fp32
    const float* __restrict__ upwt,   // [16][O]
    __bf16* __restrict__ zcl)         // [B][HC][WC][O] bf16
{
    int idx = blockIdx.x * blockDim.x + threadIdx.x;
    int x  = idx & (WC - 1);
    int y  = (idx >> 8) & (HC - 1);
    int cg = (idx >> 15) & 15;
    int b  = idx >> 19;

    int sy0, iy0, sy1, iy1, sx0, ix0, sx1, ix1;
    if (y & 1) { sy0 = (y - 1) >> 1; iy0 = 2; sy1 = sy0 + 1; iy1 = 0; }
    else       { sy0 = (y >> 1) - 1; iy0 = 3; sy1 = sy0 + 1; iy1 = 1; }
    if (x & 1) { sx0 = (x - 1) >> 1; ix0 = 2; sx1 = sx0 + 1; ix1 = 0; }
    else       { sx0 = (x >> 1) - 1; ix0 = 3; sx1 = sx0 + 1; ix1 = 1; }

    int c0 = cg * 8;
    float acc[8];
    const float* pp = prex + ((size_t)b * OO + c0) * (HC * WC) + (size_t)y * WC + x;
#pragma unroll
    for (int j = 0; j < 8; j++) acc[j] = pp[(size_t)j * HC * WC];

    bool y0v = sy0 >= 0, y1v = sy1 < HA;
    bool x0v = sx0 >= 0, x1v = sx1 < WA;
    const __bf16* hb = h1cl + (size_t)b * HA * WA * OO + c0;

    auto tap = [&](int sy, int sx, int wi) {
        uint4 u = *reinterpret_cast<const uint4*>(hb + ((size_t)sy * WA + sx) * OO);
        bf16x8 v = __builtin_bit_cast(bf16x8, u);
        const float* wp = upwt + wi * OO + c0;
#pragma unroll
        for (int j = 0; j < 8; j++) acc[j] += (float)v[j] * wp[j];
    };
    if (y0v && x0v) tap(sy0, sx0, iy0 * 4 + ix0);
    if (y0v && x1v) tap(sy0, sx1, iy0 * 4 + ix1);
    if (y1v && x0v) tap(sy1, sx0, iy1 * 4 + ix0);
    if (y1v && x1v) tap(sy1, sx1, iy1 * 4 + ix1);

    bf16x8 r;
#pragma unroll
    for (int j = 0; j < 8; j++) r[j] = (__bf16)acc[j];
    *reinterpret_cast<bf16x8*>(zcl + (((size_t)b * HC + y) * WC + x) * OO + c0) = r;
}

// ---------------- launch ----------------
extern "C" void kernel_launch(void* const* d_in, const int* in_sizes, int n_in,
                              void* d_out, int out_size, void* d_ws, size_t ws_size,
                              hipStream_t stream) {
    (void)in_sizes; (void)n_in; (void)out_size; (void)ws_size;
    const float* x      = (const float*)d_in[0];
    const float* pre_x  = (const float*)d_in[1];
    const float* pwom   = (const float*)d_in[2];
    const float* pbom   = (const float*)d_in[3];
    const float* pw     = (const float*)d_in[4];
    const float* pb     = (const float*)d_in[5];
    const float* pgam   = (const float*)d_in[6];
    const float* pbet   = (const float*)d_in[7];
    const float* pmea   = (const float*)d_in[8];
    const float* pvar   = (const float*)d_in[9];
    const float* nwom   = (const float*)d_in[10];
    const float* nbom   = (const float*)d_in[11];
    const float* nw     = (const float*)d_in[12];
    const float* nb     = (const float*)d_in[13];
    const float* ngam   = (const float*)d_in[14];
    const float* nbet   = (const float*)d_in[15];
    const float* nmea   = (const float*)d_in[16];
    const float* nvar   = (const float*)d_in[17];
    const float* upw    = (const float*)d_in[18];
    float* out = (float*)d_out;

    char* wsb = (char*)d_ws;
    __bf16* xclA  = (__bf16*)(wsb + 0);          //  8,388,608 B
    __bf16* h1cl  = (__bf16*)(wsb + 8388608);    //  4,194,304
    __bf16* zcl   = (__bf16*)(wsb + 12582912);   // 16,777,216
    float*  omA   = (float*) (wsb + 29360128);   //  2,097,152
    float*  omC   = (float*) (wsb + 31457280);   //  8,388,608
    __bf16* wkAp  = (__bf16*)(wsb + 39845888);   //    589,824
    __bf16* wkCp  = (__bf16*)(wsb + 40435712);   //    294,912
    __bf16* womAp = (__bf16*)(wsb + 40730624);   //    147,456
    __bf16* womCp = (__bf16*)(wsb + 40878080);   //     73,728
    float*  upwt  = (float*) (wsb + 40951808);   //      8,192
    float*  scA   = (float*) (wsb + 40960000);
    float*  shA   = (float*) (wsb + 40960512);
    float*  scC   = (float*) (wsb + 40961024);
    float*  shC   = (float*) (wsb + 40961536);   // end ~41.0 MB

    // prepacks
    pack_w_kernel<<<1152, 256, 0, stream>>>(pw, wkAp, CA, 8, 128);
    pack_w_kernel<<<576, 256, 0, stream>>>(nw, wkCp, CC, 8, 128);
    pack_w_kernel<<<288, 256, 0, stream>>>(pwom, womAp, CA, 2, 27);
    pack_w_kernel<<<144, 256, 0, stream>>>(nwom, womCp, CC, 2, 27);
    bn_prepack_kernel<<<1, 128, 0, stream>>>(pgam, pbet, pmea, pvar, pb, scA, shA);
    bn_prepack_kernel<<<1, 128, 0, stream>>>(ngam, nbet, nmea, nvar, nb, scC, shC);
    pack_upw_kernel<<<8, 256, 0, stream>>>(upw, upwt);
    to_cl_kernel<CA, HA*WA><<<BN2 * (CA/32) * (HA*WA/64), 256, 0, stream>>>(x, xclA);

    // stage A
    om_mfma_kernel<CA, HA, WA><<<BN2 * HA * (WA/64), 256, 0, stream>>>(xclA, womAp, pbom, omA);
    dcn_mfma6_kernel<CA, HA, WA, 4, false><<<BN2 * HA * (WA/16), 256, 0, stream>>>(
        xclA, omA, wkAp, scA, shA, nullptr, h1cl);

    // upsample + residual
    upsample_cl_kernel<<<(BN2 * 16 * HC * WC) / 256, 256, 0, stream>>>(h1cl, pre_x, upwt, zcl);

    // stage C
    om_mfma_kernel<CC, HC, WC><<<BN2 * HC * (WC/64), 256, 0, stream>>>(zcl, womCp, nbom, omC);
    dcn_mfma10_kernel<CC, HC, WC, true><<<BN2 * HC * (WC/16) / 4, 256, 0, stream>>>(
        zcl, omC, wkCp, scC, shC, out, nullptr);
}

// Round 20
// 178.282 us; speedup vs baseline: 1.3418x; 1.0017x over previous
//
#include <hip/hip_runtime.h>
#include <hip/hip_bf16.h>
#include <math.h>

typedef __bf16 bf16x8 __attribute__((ext_vector_type(8)));
typedef float  f32x4  __attribute__((ext_vector_type(4)));

static constexpr int BN2 = 2;
static constexpr int CA = 256, HA = 64, WA = 128;   // stage A input
static constexpr int OO = 128;                      // output channels
static constexpr int HC = 128, WC = 256, CC = 128;  // stage C

// ---------- pack weights into MFMA B-fragment layout: [9][C/32][OT][64][8] bf16 ----------
__global__ void pack_w_kernel(const float* __restrict__ w, __bf16* __restrict__ out,
                              int Cin, int OT, int Oreal) {
    int NCH = Cin / 32;
    int idx = blockIdx.x * blockDim.x + threadIdx.x;
    int total = 9 * NCH * OT * 512;
    if (idx >= total) return;
    int j    = idx & 7;
    int lane = (idx >> 3) & 63;
    int ot   = (idx >> 9) % OT;
    int rest = (idx >> 9) / OT;
    int ch = rest % NCH;
    int k  = rest / NCH;
    int o = ot * 16 + (lane & 15);
    int c = ch * 32 + (lane >> 4) * 8 + j;
    float v = (o < Oreal) ? w[((size_t)o * Cin + c) * 9 + k] : 0.f;
    out[idx] = (__bf16)v;
}

// ---------- NCHW fp32 -> NHWC bf16 (LDS tile transpose) ----------
template<int C, int HW>
__global__ __launch_bounds__(256) void to_cl_kernel(const float* __restrict__ x,
                                                    __bf16* __restrict__ xcl) {
    constexpr int NCB = C / 32;
    constexpr int NPB = HW / 64;
    int blk = blockIdx.x;
    int pblk = blk % NPB;
    int cblk = (blk / NPB) % NCB;
    int b = blk / (NPB * NCB);
    int t = threadIdx.x;
    __shared__ float st[32][65];
    int r = t >> 6, q = t & 63;
#pragma unroll
    for (int i = 0; i < 8; i++) {
        int c = cblk * 32 + i * 4 + r;
        st[i * 4 + r][q] = x[((size_t)b * C + c) * HW + pblk * 64 + q];
    }
    __syncthreads();
    int p = t >> 2, cq = t & 3;
    bf16x8 v;
#pragma unroll
    for (int j = 0; j < 8; j++) v[j] = (__bf16)st[cq * 8 + j][p];
    *reinterpret_cast<bf16x8*>(xcl + ((size_t)b * HW + pblk * 64 + p) * C + cblk * 32 + cq * 8) = v;
}

// ---------- fold bias+BN into per-o scale/shift ----------
__global__ void bn_prepack_kernel(const float* __restrict__ g,  const float* __restrict__ be,
                                  const float* __restrict__ mu, const float* __restrict__ va,
                                  const float* __restrict__ bi,
                                  float* __restrict__ sc, float* __restrict__ sh) {
    int i = blockIdx.x * blockDim.x + threadIdx.x;
    if (i >= OO) return;
    float s = g[i] * rsqrtf(va[i] + 1e-5f);
    sc[i] = s;
    sh[i] = (bi[i] - mu[i]) * s + be[i];
}

// ---------- upw[O][4][4] -> upwt[16][O] ----------
__global__ void pack_upw_kernel(const float* __restrict__ upw, float* __restrict__ upwt) {
    int idx = blockIdx.x * blockDim.x + threadIdx.x;
    if (idx >= 16 * OO) return;
    int i = idx >> 7;
    int o = idx & 127;
    upwt[i * OO + o] = upw[o * 16 + i];
}

// ---------- om-conv as MFMA, pixel-major window (r18-proven) ----------
template<int C, int H, int W>
__global__ __launch_bounds__(256) void om_mfma_kernel(
    const __bf16* __restrict__ xcl,   // [B][H][W][C]
    const __bf16* __restrict__ womp,  // [9][C/32][2][64][8] bf16
    const float* __restrict__ bom,    // [27]
    float* __restrict__ omcl)         // [B][H][W][32]
{
    constexpr int NCH = C / 32;
    constexpr int RS = 36;
    const int nwt = W / 64;
    int wt = blockIdx.x % nwt;
    int h  = (blockIdx.x / nwt) % H;
    int b  = blockIdx.x / (nwt * H);
    int t = threadIdx.x;
    int wave = t >> 6, lane = t & 63;
    int row = lane & 15, kg = lane >> 4;

    __shared__ __bf16 win[198 * RS];   // 14256 B

    f32x4 acc0 = {0.f, 0.f, 0.f, 0.f};
    f32x4 acc1 = {0.f, 0.f, 0.f, 0.f};
    const __bf16* xb = xcl + (size_t)b * H * W * C;

    for (int ch = 0; ch < NCH; ch++) {
        for (int i = 0; i < 4; i++) {
            int idx = i * 256 + t;
            if (idx < 792) {
                int cq  = idx & 3;
                int pix = idx >> 2;
                int ry = pix / 66, rx = pix % 66;
                int y = h + ry - 1, xx = wt * 64 + rx - 1;
                bool valid = (y >= 0) && (y < H) && (xx >= 0) && (xx < W);
                int yc = min(max(y, 0), H - 1), xc = min(max(xx, 0), W - 1);
                uint4 u = *reinterpret_cast<const uint4*>(
                    xb + ((size_t)yc * W + xc) * C + ch * 32 + cq * 8);
                if (!valid) { u.x = 0; u.y = 0; u.z = 0; u.w = 0; }
                *reinterpret_cast<uint4*>(&win[pix * RS + cq * 8]) = u;
            }
        }
        __syncthreads();
#pragma unroll
        for (int k = 0; k < 9; k++) {
            int off = (k / 3) * 66 + (k % 3) + wave * 16 + row;
            bf16x8 a = *reinterpret_cast<const bf16x8*>(&win[off * RS + kg * 8]);
            const __bf16* wbc = womp + ((size_t)k * NCH + ch) * 1024 + lane * 8;
            bf16x8 b0 = *reinterpret_cast<const bf16x8*>(wbc);
            bf16x8 b1 = *reinterpret_cast<const bf16x8*>(wbc + 512);
            acc0 = __builtin_amdgcn_mfma_f32_16x16x32_bf16(a, b0, acc0, 0, 0, 0);
            acc1 = __builtin_amdgcn_mfma_f32_16x16x32_bf16(a, b1, acc1, 0, 0, 0);
        }
        __syncthreads();
    }

    float* ob = omcl + (((size_t)b * H + h) * W + wt * 64 + wave * 16 + kg * 4) * 32;
    float bb0 = bom[row];
#pragma unroll
    for (int j = 0; j < 4; j++)
        ob[(size_t)j * 32 + row] = acc0[j] + bb0;
    if (row < 11) {
        float bb1 = bom[16 + row];
#pragma unroll
        for (int j = 0; j < 4; j++)
            ob[(size_t)j * 32 + 16 + row] = acc1[j] + bb1;
    }
}

// ---------- DCN v6 (proven): 16-pos tiles + split-K + B-prefetch (stage A) ----------
template<int C, int H, int W, int KS, bool CF_OUT>
__global__ __launch_bounds__(64 * KS) void dcn_mfma6_kernel(
    const __bf16* __restrict__ xcl,  // [B][H][W][C]
    const float* __restrict__ omcl,  // [B][H][W][32]
    const __bf16* __restrict__ wkp,  // [9][C/32][8][64][8] bf16 (pack_w)
    const float* __restrict__ sc, const float* __restrict__ sh,
    float* __restrict__ outcf,       // CF_OUT: [B][O][H][W] fp32
    __bf16* __restrict__ outcl)      // else:   [B][H][W][O] bf16
{
    constexpr int NCH = C / 32;
    constexpr int CHW = NCH / KS;
    constexpr int NSW = 9 * CHW;
    static_assert(NSW % 2 == 0, "unroll-by-2 needs even NSW");
    constexpr int MAIN = 4608 + KS * 2560;
    constexpr int RED  = (KS - 1) * 9216;
    constexpr int SMEM = MAIN > RED ? MAIN : RED;

    const int nwt = W / 16;
    int wt = blockIdx.x % nwt;
    int h  = (blockIdx.x / nwt) % H;
    int b  = blockIdx.x / (nwt * H);
    int t = threadIdx.x;
    int wave = t >> 6, lane = t & 63;
    int row = lane & 15, kg = lane >> 4;
    int pos16 = lane >> 2, cq = lane & 3;

    __shared__ __align__(16) char smem[SMEM];
    int4*   pki  = reinterpret_cast<int4*>(smem);            // [144]
    float4* pkw  = reinterpret_cast<float4*>(smem + 2304);   // [144]
    __bf16* sbuf = reinterpret_cast<__bf16*>(smem + 4608);   // [KS][2][16*40]

    const float* omb = omcl + (((size_t)b * H + h) * W + wt * 16) * 32;
    for (int idx = t; idx < 144; idx += 64 * KS) {
        int p = idx & 15;
        int k = idx >> 4;
        float o1 = omb[p * 32 + k];
        float o2 = omb[p * 32 + 9 + k];
        float mm = omb[p * 32 + 18 + k];
        mm = 1.f / (1.f + expf(-mm));
        float py = o1 + (float)(h + k / 3 - 1);
        float px = o2 + (float)(wt * 16 + p + k % 3 - 1);
        float y0f = floorf(py), x0f = floorf(px);
        float wy = py - y0f, wx = px - x0f;
        int y0 = (int)y0f, x0 = (int)x0f;
        bool y0v = (y0 >= 0) && (y0 < H);
        bool y1v = (y0 + 1 >= 0) && (y0 + 1 < H);
        bool x0v = (x0 >= 0) && (x0 < W);
        bool x1v = (x0 + 1 >= 0) && (x0 + 1 < W);
        int y0c = min(max(y0, 0), H - 1) * W;
        int y1c = min(max(y0 + 1, 0), H - 1) * W;
        int x0c = min(max(x0, 0), W - 1);
        int x1c = min(max(x0 + 1, 0), W - 1);
        int4 pi;
        pi.x = (y0c + x0c) * C; pi.y = (y0c + x1c) * C;
        pi.z = (y1c + x0c) * C; pi.w = (y1c + x1c) * C;
        float4 pw;
        pw.x = (y0v && x0v) ? (1.f - wy) * (1.f - wx) * mm : 0.f;
        pw.y = (y0v && x1v) ? (1.f - wy) * wx * mm : 0.f;
        pw.z = (y1v && x0v) ? wy * (1.f - wx) * mm : 0.f;
        pw.w = (y1v && x1v) ? wy * wx * mm : 0.f;
        pki[idx] = pi;
        pkw[idx] = pw;
    }
    __syncthreads();

    f32x4 acc[8];
#pragma unroll
    for (int i = 0; i < 8; i++) acc[i] = {0.f, 0.f, 0.f, 0.f};

    const __bf16* xb = xcl + (size_t)b * H * W * C;
    __bf16* sb = sbuf + wave * 1280;
    __bf16* wp0 = sb + pos16 * 40 + cq * 8;
    const __bf16* rp0 = sb + row * 40 + kg * 8;

    uint4 u00, u01, u10, u11;
    float4 pwc;
    bf16x8 Ba[8], Bb[8];

    auto LOADG = [&](int ls) {
        int k = ls / CHW, chl = ls - k * CHW;
        int4 pi = pki[k * 16 + pos16];
        pwc = pkw[k * 16 + pos16];
        int cb = (wave * CHW + chl) * 32 + cq * 8;
        u00 = *reinterpret_cast<const uint4*>(xb + pi.x + cb);
        u01 = *reinterpret_cast<const uint4*>(xb + pi.y + cb);
        u10 = *reinterpret_cast<const uint4*>(xb + pi.z + cb);
        u11 = *reinterpret_cast<const uint4*>(xb + pi.w + cb);
    };
    auto LOADBA = [&](int ls) {
        int k = ls / CHW, chl = ls - k * CHW;
        int sg = k * NCH + wave * CHW + chl;
        const __bf16* wbc = wkp + (size_t)sg * 4096 + lane * 8;
#pragma unroll
        for (int ot = 0; ot < 8; ot++)
            Ba[ot] = *reinterpret_cast<const bf16x8*>(wbc + ot * 512);
    };
    auto LOADBB = [&](int ls) {
        int k = ls / CHW, chl = ls - k * CHW;
        int sg = k * NCH + wave * CHW + chl;
        const __bf16* wbc = wkp + (size_t)sg * 4096 + lane * 8;
#pragma unroll
        for (int ot = 0; ot < 8; ot++)
            Bb[ot] = *reinterpret_cast<const bf16x8*>(wbc + ot * 512);
    };
    auto BLEND = [&](int bufoff) {
        bf16x8 v00 = __builtin_bit_cast(bf16x8, u00);
        bf16x8 v01 = __builtin_bit_cast(bf16x8, u01);
        bf16x8 v10 = __builtin_bit_cast(bf16x8, u10);
        bf16x8 v11 = __builtin_bit_cast(bf16x8, u11);
        bf16x8 rg;
#pragma unroll
        for (int j = 0; j < 8; j++) {
            float sv = pwc.x * (float)v00[j] + pwc.y * (float)v01[j]
                     + pwc.z * (float)v10[j] + pwc.w * (float)v11[j];
            rg[j] = (__bf16)sv;
        }
        *reinterpret_cast<bf16x8*>(wp0 + bufoff) = rg;
    };
    auto MFMAA = [&](int bufoff) {
        bf16x8 a = *reinterpret_cast<const bf16x8*>(rp0 + bufoff);
#pragma unroll
        for (int ot = 0; ot < 8; ot++)
            acc[ot] = __builtin_amdgcn_mfma_f32_16x16x32_bf16(a, Ba[ot], acc[ot], 0, 0, 0);
    };
    auto MFMAB = [&](int bufoff) {
        bf16x8 a = *reinterpret_cast<const bf16x8*>(rp0 + bufoff);
#pragma unroll
        for (int ot = 0; ot < 8; ot++)
            acc[ot] = __builtin_amdgcn_mfma_f32_16x16x32_bf16(a, Bb[ot], acc[ot], 0, 0, 0);
    };

    LOADBA(0);
    LOADG(0);
    for (int s = 0; s < NSW; s += 2) {
        BLEND(0);
        LOADBB(s + 1);
        LOADG(s + 1);
        MFMAA(0);
        BLEND(640);
        if (s + 2 < NSW) { LOADBA(s + 2); LOADG(s + 2); }
        MFMAB(640);
    }

    __syncthreads();
    if (wave > 0) {
        float* rd = reinterpret_cast<float*>(smem) + (wave - 1) * 2304;
#pragma unroll
        for (int ot = 0; ot < 8; ot++)
            *reinterpret_cast<f32x4*>(rd + lane * 36 + ot * 4) = acc[ot];
    }
    __syncthreads();
    if (wave == 0) {
        for (int s = 0; s < KS - 1; s++) {
            float* rd = reinterpret_cast<float*>(smem) + s * 2304;
#pragma unroll
            for (int ot = 0; ot < 8; ot++) {
                f32x4 v = *reinterpret_cast<const f32x4*>(rd + lane * 36 + ot * 4);
                acc[ot] += v;
            }
        }
        if (CF_OUT) {
            float* ob = outcf + (size_t)b * OO * H * W + (size_t)h * W + wt * 16;
#pragma unroll
            for (int ot = 0; ot < 8; ot++) {
                int o = ot * 16 + row;
                float s = sc[o], hh = sh[o];
#pragma unroll
                for (int j = 0; j < 4; j++) {
                    float y = fmaxf(acc[ot][j] * s + hh, 0.f);
                    ob[(size_t)o * H * W + kg * 4 + j] = y;
                }
            }
        } else {
            __bf16* ob = outcl + (((size_t)b * H + h) * W + wt * 16) * OO;
#pragma unroll
            for (int ot = 0; ot < 8; ot++) {
                int o = ot * 16 + row;
                float s = sc[o], hh = sh[o];
#pragma unroll
                for (int j = 0; j < 4; j++) {
                    float y = fmaxf(acc[ot][j] * s + hh, 0.f);
                    ob[(size_t)(kg * 4 + j) * OO + o] = (__bf16)y;
                }
            }
        }
    }
}

// ---------- DCN v11 (stage C): 4 wave-tiles + shared B, 2-step pair staging ----------
// r19 structure with the LDS size bug fixed: Bbuf = 2 pairs x 2 steps x 4096 bf16
// = 32768 bf16 = 65536B/2... = 32768 BYTES (was wrongly 16384).
template<int C, int H, int W, bool CF_OUT>
__global__ __launch_bounds__(256) void dcn_mfma11_kernel(
    const __bf16* __restrict__ xcl,  // [B][H][W][C]
    const float* __restrict__ omcl,  // [B][H][W][32]
    const __bf16* __restrict__ wkp,  // [9][C/32][8][64][8] bf16 (pack_w)
    const float* __restrict__ sc, const float* __restrict__ sh,
    float* __restrict__ outcf,       // CF_OUT: [B][O][H][W] fp32
    __bf16* __restrict__ outcl)      // else:   [B][H][W][O] bf16
{
    constexpr int NCH = C / 32;
    constexpr int NSW = 9 * NCH;     // 36 for C=128
    static_assert(NSW % 2 == 0, "pair loop needs even NSW");

    int t = threadIdx.x;
    int wave = t >> 6, lane = t & 63;
    int row = lane & 15, kg = lane >> 4;
    int pos16 = lane >> 2, cq = lane & 3;

    __shared__ __align__(16) char smem[4 * 7168 + 32768];   // per-wave ws + B pair dbuf (FIXED SIZE)
    char* ws = smem + wave * 7168;
    int4*   pki  = reinterpret_cast<int4*>(ws);             // [144]
    float4* pkw  = reinterpret_cast<float4*>(ws + 2304);    // [144]
    __bf16* sb   = reinterpret_cast<__bf16*>(ws + 4608);    // [2][640]
    __bf16* Bbuf = reinterpret_cast<__bf16*>(smem + 28672); // [2 pairs][2 steps][4096] bf16

    const int nwt = W / 16;
    int tile = blockIdx.x * 4 + wave;
    int wt = tile % nwt;
    int h  = (tile / nwt) % H;
    int b  = tile / (nwt * H);

    const float* omb = omcl + (((size_t)b * H + h) * W + wt * 16) * 32;
    for (int idx = lane; idx < 144; idx += 64) {
        int p = idx & 15;
        int k = idx >> 4;
        float o1 = omb[p * 32 + k];
        float o2 = omb[p * 32 + 9 + k];
        float mm = omb[p * 32 + 18 + k];
        mm = 1.f / (1.f + expf(-mm));
        float py = o1 + (float)(h + k / 3 - 1);
        float px = o2 + (float)(wt * 16 + p + k % 3 - 1);
        float y0f = floorf(py), x0f = floorf(px);
        float wy = py - y0f, wx = px - x0f;
        int y0 = (int)y0f, x0 = (int)x0f;
        bool y0v = (y0 >= 0) && (y0 < H);
        bool y1v = (y0 + 1 >= 0) && (y0 + 1 < H);
        bool x0v = (x0 >= 0) && (x0 < W);
        bool x1v = (x0 + 1 >= 0) && (x0 + 1 < W);
        int y0c = min(max(y0, 0), H - 1) * W;
        int y1c = min(max(y0 + 1, 0), H - 1) * W;
        int x0c = min(max(x0, 0), W - 1);
        int x1c = min(max(x0 + 1, 0), W - 1);
        int4 pi;
        pi.x = (y0c + x0c) * C; pi.y = (y0c + x1c) * C;
        pi.z = (y1c + x0c) * C; pi.w = (y1c + x1c) * C;
        float4 pw;
        pw.x = (y0v && x0v) ? (1.f - wy) * (1.f - wx) * mm : 0.f;
        pw.y = (y0v && x1v) ? (1.f - wy) * wx * mm : 0.f;
        pw.z = (y1v && x0v) ? wy * (1.f - wx) * mm : 0.f;
        pw.w = (y1v && x1v) ? wy * wx * mm : 0.f;
        pki[idx] = pi;
        pkw[idx] = pw;
    }

    f32x4 acc[8];
#pragma unroll
    for (int i = 0; i < 8; i++) acc[i] = {0.f, 0.f, 0.f, 0.f};

    const __bf16* xb = xcl + (size_t)b * H * W * C;
    __bf16* wp0 = sb + pos16 * 40 + cq * 8;
    const __bf16* rp0 = sb + row * 40 + kg * 8;

    uint4 u00, u01, u10, u11;
    float4 pwc;

    auto LOADG = [&](int ls) {
        int k = ls / NCH, chl = ls - k * NCH;
        int4 pi = pki[k * 16 + pos16];
        pwc = pkw[k * 16 + pos16];
        int cb = chl * 32 + cq * 8;
        u00 = *reinterpret_cast<const uint4*>(xb + pi.x + cb);
        u01 = *reinterpret_cast<const uint4*>(xb + pi.y + cb);
        u10 = *reinterpret_cast<const uint4*>(xb + pi.z + cb);
        u11 = *reinterpret_cast<const uint4*>(xb + pi.w + cb);
    };
    auto BLEND = [&](int bufoff) {
        bf16x8 v00 = __builtin_bit_cast(bf16x8, u00);
        bf16x8 v01 = __builtin_bit_cast(bf16x8, u01);
        bf16x8 v10 = __builtin_bit_cast(bf16x8, u10);
        bf16x8 v11 = __builtin_bit_cast(bf16x8, u11);
        bf16x8 rg;
#pragma unroll
        for (int j = 0; j < 8; j++) {
            float sv = pwc.x * (float)v00[j] + pwc.y * (float)v01[j]
                     + pwc.z * (float)v10[j] + pwc.w * (float)v11[j];
            rg[j] = (__bf16)sv;
        }
        *reinterpret_cast<bf16x8*>(wp0 + bufoff) = rg;
    };

    // prologue: stage pair0 (steps 0,1) into Bbuf[0]; gathers(0)
    {
        const __bf16* s0 = wkp + (size_t)0 * 4096 + wave * 1024 + lane * 8;
        const __bf16* s1 = wkp + (size_t)1 * 4096 + wave * 1024 + lane * 8;
        uint4 a0 = *reinterpret_cast<const uint4*>(s0);
        uint4 a1 = *reinterpret_cast<const uint4*>(s0 + 512);
        uint4 a2 = *reinterpret_cast<const uint4*>(s1);
        uint4 a3 = *reinterpret_cast<const uint4*>(s1 + 512);
        LOADG(0);
        __bf16* d0 = Bbuf + wave * 1024;
        *reinterpret_cast<uint4*>(d0 + lane * 8) = a0;
        *reinterpret_cast<uint4*>(d0 + 512 + lane * 8) = a1;
        *reinterpret_cast<uint4*>(d0 + 4096 + lane * 8) = a2;
        *reinterpret_cast<uint4*>(d0 + 4096 + 512 + lane * 8) = a3;
    }

    for (int s = 0; s < NSW; s += 2) {
        __syncthreads();                       // pair p=(s>>1)&1 staged
        int poff = ((s >> 1) & 1) * 8192;
        bool st = (s + 2 < NSW);
        uint4 a0, a1, a2, a3;
        if (st) {   // issue next-pair stage loads (coalesced)
            const __bf16* s0 = wkp + (size_t)(s + 2) * 4096 + wave * 1024 + lane * 8;
            const __bf16* s1 = wkp + (size_t)(s + 3) * 4096 + wave * 1024 + lane * 8;
            a0 = *reinterpret_cast<const uint4*>(s0);
            a1 = *reinterpret_cast<const uint4*>(s0 + 512);
            a2 = *reinterpret_cast<const uint4*>(s1);
            a3 = *reinterpret_cast<const uint4*>(s1 + 512);
        }
        // step s (even): sbuf buf0
        {
            bf16x8 Breg[8];
#pragma unroll
            for (int ot = 0; ot < 8; ot++)
                Breg[ot] = *reinterpret_cast<const bf16x8*>(Bbuf + poff + ot * 512 + lane * 8);
            BLEND(0);
            LOADG(s + 1);
            bf16x8 a = *reinterpret_cast<const bf16x8*>(rp0);
#pragma unroll
            for (int ot = 0; ot < 8; ot++)
                acc[ot] = __builtin_amdgcn_mfma_f32_16x16x32_bf16(a, Breg[ot], acc[ot], 0, 0, 0);
        }
        // step s+1 (odd): sbuf buf1
        {
            bf16x8 Breg[8];
#pragma unroll
            for (int ot = 0; ot < 8; ot++)
                Breg[ot] = *reinterpret_cast<const bf16x8*>(Bbuf + poff + 4096 + ot * 512 + lane * 8);
            BLEND(640);
            if (st) LOADG(s + 2);
            bf16x8 a = *reinterpret_cast<const bf16x8*>(rp0 + 640);
#pragma unroll
            for (int ot = 0; ot < 8; ot++)
                acc[ot] = __builtin_amdgcn_mfma_f32_16x16x32_bf16(a, Breg[ot], acc[ot], 0, 0, 0);
        }
        if (st) {   // write staged pair into Bbuf[p^1]
            __bf16* d0 = Bbuf + (poff ^ 8192) + wave * 1024;
            *reinterpret_cast<uint4*>(d0 + lane * 8) = a0;
            *reinterpret_cast<uint4*>(d0 + 512 + lane * 8) = a1;
            *reinterpret_cast<uint4*>(d0 + 4096 + lane * 8) = a2;
            *reinterpret_cast<uint4*>(d0 + 4096 + 512 + lane * 8) = a3;
        }
    }

    // epilogue, D map: o = ot*16+row, pos = kg*4+j
    if (CF_OUT) {
        float* ob = outcf + (size_t)b * OO * H * W + (size_t)h * W + wt * 16;
#pragma unroll
        for (int ot = 0; ot < 8; ot++) {
            int o = ot * 16 + row;
            float s = sc[o], hh = sh[o];
#pragma unroll
            for (int j = 0; j < 4; j++) {
                float y = fmaxf(acc[ot][j] * s + hh, 0.f);
                ob[(size_t)o * H * W + kg * 4 + j] = y;
            }
        }
    } else {
        __bf16* ob = outcl + (((size_t)b * H + h) * W + wt * 16) * OO;
#pragma unroll
        for (int ot = 0; ot < 8; ot++) {
            int o = ot * 16 + row;
            float s = sc[o], hh = sh[o];
#pragma unroll
            for (int j = 0; j < 4; j++) {
                float y = fmaxf(acc[ot][j] * s + hh, 0.f);
                ob[(size_t)(kg * 4 + j) * OO + o] = (__bf16)y;
            }
        }
    }
}

// ---------- bilinear x2 depthwise transposed conv + residual ----------
__global__ __launch_bounds__(256) void upsample_cl_kernel(
    const __bf16* __restrict__ h1cl,  // [B][HA][WA][O] bf16
    const float* __restrict__ prex,   // [B][O][HC][WC] fp32
    const float* __restrict__ upwt,   // [16][O]
    __bf16* __restrict__ zcl)         // [B][HC][WC][O] bf16
{
    int idx = blockIdx.x * blockDim.x + threadIdx.x;
    int x  = idx & (WC - 1);
    int y  = (idx >> 8) & (HC - 1);
    int cg = (idx >> 15) & 15;
    int b  = idx >> 19;

    int sy0, iy0, sy1, iy1, sx0, ix0, sx1, ix1;
    if (y & 1) { sy0 = (y - 1) >> 1; iy0 = 2; sy1 = sy0 + 1; iy1 = 0; }
    else       { sy0 = (y >> 1) - 1; iy0 = 3; sy1 = sy0 + 1; iy1 = 1; }
    if (x & 1) { sx0 = (x - 1) >> 1; ix0 = 2; sx1 = sx0 + 1; ix1 = 0; }
    else       { sx0 = (x >> 1) - 1; ix0 = 3; sx1 = sx0 + 1; ix1 = 1; }

    int c0 = cg * 8;
    float acc[8];
    const float* pp = prex + ((size_t)b * OO + c0) * (HC * WC) + (size_t)y * WC + x;
#pragma unroll
    for (int j = 0; j < 8; j++) acc[j] = pp[(size_t)j * HC * WC];

    bool y0v = sy0 >= 0, y1v = sy1 < HA;
    bool x0v = sx0 >= 0, x1v = sx1 < WA;
    const __bf16* hb = h1cl + (size_t)b * HA * WA * OO + c0;

    auto tap = [&](int sy, int sx, int wi) {
        uint4 u = *reinterpret_cast<const uint4*>(hb + ((size_t)sy * WA + sx) * OO);
        bf16x8 v = __builtin_bit_cast(bf16x8, u);
        const float* wp = upwt + wi * OO + c0;
#pragma unroll
        for (int j = 0; j < 8; j++) acc[j] += (float)v[j] * wp[j];
    };
    if (y0v && x0v) tap(sy0, sx0, iy0 * 4 + ix0);
    if (y0v && x1v) tap(sy0, sx1, iy0 * 4 + ix1);
    if (y1v && x0v) tap(sy1, sx0, iy1 * 4 + ix0);
    if (y1v && x1v) tap(sy1, sx1, iy1 * 4 + ix1);

    bf16x8 r;
#pragma unroll
    for (int j = 0; j < 8; j++) r[j] = (__bf16)acc[j];
    *reinterpret_cast<bf16x8*>(zcl + (((size_t)b * HC + y) * WC + x) * OO + c0) = r;
}

// ---------------- launch ----------------
extern "C" void kernel_launch(void* const* d_in, const int* in_sizes, int n_in,
                              void* d_out, int out_size, void* d_ws, size_t ws_size,
                              hipStream_t stream) {
    (void)in_sizes; (void)n_in; (void)out_size; (void)ws_size;
    const float* x      = (const float*)d_in[0];
    const float* pre_x  = (const float*)d_in[1];
    const float* pwom   = (const float*)d_in[2];
    const float* pbom   = (const float*)d_in[3];
    const float* pw     = (const float*)d_in[4];
    const float* pb     = (const float*)d_in[5];
    const float* pgam   = (const float*)d_in[6];
    const float* pbet   = (const float*)d_in[7];
    const float* pmea   = (const float*)d_in[8];
    const float* pvar   = (const float*)d_in[9];
    const float* nwom   = (const float*)d_in[10];
    const float* nbom   = (const float*)d_in[11];
    const float* nw     = (const float*)d_in[12];
    const float* nb     = (const float*)d_in[13];
    const float* ngam   = (const float*)d_in[14];
    const float* nbet   = (const float*)d_in[15];
    const float* nmea   = (const float*)d_in[16];
    const float* nvar   = (const float*)d_in[17];
    const float* upw    = (const float*)d_in[18];
    float* out = (float*)d_out;

    char* wsb = (char*)d_ws;
    __bf16* xclA  = (__bf16*)(wsb + 0);          //  8,388,608 B
    __bf16* h1cl  = (__bf16*)(wsb + 8388608);    //  4,194,304
    __bf16* zcl   = (__bf16*)(wsb + 12582912);   // 16,777,216
    float*  omA   = (float*) (wsb + 29360128);   //  2,097,152
    float*  omC   = (float*) (wsb + 31457280);   //  8,388,608
    __bf16* wkAp  = (__bf16*)(wsb + 39845888);   //    589,824
    __bf16* wkCp  = (__bf16*)(wsb + 40435712);   //    294,912
    __bf16* womAp = (__bf16*)(wsb + 40730624);   //    147,456
    __bf16* womCp = (__bf16*)(wsb + 40878080);   //     73,728
    float*  upwt  = (float*) (wsb + 40951808);   //      8,192
    float*  scA   = (float*) (wsb + 40960000);
    float*  shA   = (float*) (wsb + 40960512);
    float*  scC   = (float*) (wsb + 40961024);
    float*  shC   = (float*) (wsb + 40961536);   // end ~41.0 MB

    // prepacks
    pack_w_kernel<<<1152, 256, 0, stream>>>(pw, wkAp, CA, 8, 128);
    pack_w_kernel<<<576, 256, 0, stream>>>(nw, wkCp, CC, 8, 128);
    pack_w_kernel<<<288, 256, 0, stream>>>(pwom, womAp, CA, 2, 27);
    pack_w_kernel<<<144, 256, 0, stream>>>(nwom, womCp, CC, 2, 27);
    bn_prepack_kernel<<<1, 128, 0, stream>>>(pgam, pbet, pmea, pvar, pb, scA, shA);
    bn_prepack_kernel<<<1, 128, 0, stream>>>(ngam, nbet, nmea, nvar, nb, scC, shC);
    pack_upw_kernel<<<8, 256, 0, stream>>>(upw, upwt);
    to_cl_kernel<CA, HA*WA><<<BN2 * (CA/32) * (HA*WA/64), 256, 0, stream>>>(x, xclA);

    // stage A
    om_mfma_kernel<CA, HA, WA><<<BN2 * HA * (WA/64), 256, 0, stream>>>(xclA, womAp, pbom, omA);
    dcn_mfma6_kernel<CA, HA, WA, 4, false><<<BN2 * HA * (WA/16), 256, 0, stream>>>(
        xclA, omA, wkAp, scA, shA, nullptr, h1cl);

    // upsample + residual
    upsample_cl_kernel<<<(BN2 * 16 * HC * WC) / 256, 256, 0, stream>>>(h1cl, pre_x, upwt, zcl);

    // stage C — v11 (fixed LDS size): 2-step pair B staging, one barrier per 2 steps
    om_mfma_kernel<CC, HC, WC><<<BN2 * HC * (WC/64), 256, 0, stream>>>(zcl, womCp, nbom, omC);
    dcn_mfma11_kernel<CC, HC, WC, true><<<BN2 * HC * (WC/16) / 4, 256, 0, stream>>>(
        zcl, omC, wkCp, scC, shC, out, nullptr);
}